// Round 6
// baseline (187.798 us; speedup 1.0000x reference)
//
#include <hip/hip_runtime.h>

// MultiHeadSelfAttention: B=2, S=2048, E=1024, H=16, D=64
// bf16 MFMA pipeline. R14: R13 skeleton (4 waves x 32 q-rows of both tiles,
// kv-half split, LDS dbuf + bank swizzle, permlane softpack, XCD-local grid,
// pair-balanced tA) with two isolated changes:
//  (1) exp2f -> __builtin_amdgcn_exp2f: libm __ocml_exp2_f32 is ~8 VALU
//      instrs (range checks); raw v_exp_f32 is 1. 32 calls/iter/wave on the
//      serial softmax path -> cuts ~30% of iteration VALU.
//  (2) out-projection GEMM BN 64->128: 256 blocks (1/CU), halves staging
//      bytes+instrs per MFMA, zero dispatch tail.

typedef unsigned short u16;
typedef short bf16x8 __attribute__((ext_vector_type(8)));
typedef float f32x4 __attribute__((ext_vector_type(4)));
typedef unsigned short u16x4 __attribute__((ext_vector_type(4)));

#define S_LEN 2048
#define EMB 1024
#define NH 16
#define HD 64
#define QKV_W 3072
#define BATCH 2
#define CSC 0.18033688f  // 0.125 * log2(e)

static __device__ __forceinline__ u16 f2bf(float f) {
    unsigned x = __float_as_uint(f);
    return (u16)((x + 0x7fffu + ((x >> 16) & 1u)) >> 16);
}

static __device__ __forceinline__ void gld_lds16(const u16* g, u16* l) {
    __builtin_amdgcn_global_load_lds(
        (const __attribute__((address_space(1))) void*)g,
        (__attribute__((address_space(3))) void*)l, 16, 0, 0);
}

// ---------------- fused fp32 -> bf16 casts (3 ranges) ----------------
#define XN4 (BATCH * S_LEN * EMB / 4)      // 1048576
#define WQ4 (QKV_W * EMB / 4)              // 786432
#define W04 (EMB * EMB / 4)                // 262144
__global__ __launch_bounds__(256) void cvt_all(const float* __restrict__ x,
                                               const float* __restrict__ wq,
                                               const float* __restrict__ w0,
                                               u16* __restrict__ xb,
                                               u16* __restrict__ wqb,
                                               u16* __restrict__ w0b) {
    int i = blockIdx.x * 256 + threadIdx.x;
    const float* src;
    u16* dst;
    int off;
    if (i < XN4) { src = x; dst = xb; off = i; }
    else if (i < XN4 + WQ4) { src = wq; dst = wqb; off = i - XN4; }
    else { src = w0; dst = w0b; off = i - XN4 - WQ4; }
    float4 v = ((const float4*)src)[off];
    u16x4 o;
    o[0] = f2bf(v.x); o[1] = f2bf(v.y); o[2] = f2bf(v.z); o[3] = f2bf(v.w);
    ((u16x4*)dst)[off] = o;
}

// ---------------- GEMM: C[M,N] = A[M,K] @ Bt[N,K]^T ----------------
// BM=128, BN template (128 or 64), BK=32, 256 thr / 4 waves.
// Columns n < qcols scaled by CSC (Q pre-scaling for attention).
template <typename OutT, int BN>
__global__ __launch_bounds__(256) void gemm_bt(const u16* __restrict__ A,
                                               const u16* __restrict__ Bt,
                                               OutT* __restrict__ C,
                                               int M, int N, int K, int qcols) {
    constexpr int NF = BN / 32;  // n-frags per wave
    __shared__ alignas(16) u16 As[128 * 32];
    __shared__ alignas(16) u16 Bs[BN * 32];
    const int tid = threadIdx.x;
    const int wave = tid >> 6, lane = tid & 63;
    const int quad = lane >> 4, lr = lane & 15;
    const int m0 = blockIdx.y * 128, n0 = blockIdx.x * BN;
    const int wm = (wave & 1) * 64, wn = (wave >> 1) * (BN / 2);
    const float sc = (n0 < qcols) ? CSC : 1.0f;

    f32x4 acc[4][NF] = {};

    for (int k0 = 0; k0 < K; k0 += 32) {
#pragma unroll
        for (int i = 0; i < 2; ++i) {
            int chunk = tid + i * 256;
            int row = chunk >> 2;
            int col8 = (chunk & 3) * 8;
            gld_lds16(&A[(size_t)(m0 + row) * K + k0 + col8], &As[row * 32 + col8]);
        }
#pragma unroll
        for (int i = 0; i < BN / 64; ++i) {
            int chunk = tid + i * 256;
            int row = chunk >> 2;
            int col8 = (chunk & 3) * 8;
            gld_lds16(&Bt[(size_t)(n0 + row) * K + k0 + col8], &Bs[row * 32 + col8]);
        }
        __syncthreads();
        bf16x8 af[4], bf[NF];
#pragma unroll
        for (int i = 0; i < 4; ++i)
            af[i] = *(const bf16x8*)&As[(wm + i * 16 + lr) * 32 + quad * 8];
#pragma unroll
        for (int i = 0; i < NF; ++i)
            bf[i] = *(const bf16x8*)&Bs[(wn + i * 16 + lr) * 32 + quad * 8];
#pragma unroll
        for (int mi = 0; mi < 4; ++mi)
#pragma unroll
            for (int ni = 0; ni < NF; ++ni)
                acc[mi][ni] = __builtin_amdgcn_mfma_f32_16x16x32_bf16(
                    af[mi], bf[ni], acc[mi][ni], 0, 0, 0);
        __syncthreads();
    }

#pragma unroll
    for (int mi = 0; mi < 4; ++mi) {
#pragma unroll
        for (int r = 0; r < 4; ++r) {
            int gr = m0 + wm + mi * 16 + quad * 4 + r;
#pragma unroll
            for (int ni = 0; ni < NF; ++ni) {
                int gc = n0 + wn + ni * 16 + lr;
                float v = acc[mi][ni][r] * sc;
                if constexpr (sizeof(OutT) == 2)
                    C[(size_t)gr * N + gc] = (OutT)f2bf(v);
                else
                    C[(size_t)gr * N + gc] = (OutT)v;
            }
        }
    }
}

// ---------------- V transpose: qkv[.,2048+h*64+d] -> vt[bh][d][s] ----------------
__global__ __launch_bounds__(256) void transpose_v(const u16* __restrict__ qkv,
                                                   u16* __restrict__ vt) {
    __shared__ alignas(16) u16 t[64][72];
    const int s0 = blockIdx.x * 64;
    const int bh = blockIdx.y;
    const int b = bh >> 4, h = bh & 15;
#pragma unroll
    for (int i = 0; i < 2; ++i) {
        int chunk = threadIdx.x + i * 256;
        int row = chunk >> 3;
        int c8 = (chunk & 7) * 8;
        uint4 v = *(const uint4*)&qkv[(size_t)(b * S_LEN + s0 + row) * QKV_W +
                                      2 * EMB + h * HD + c8];
        const u16* p = (const u16*)&v;
#pragma unroll
        for (int jj = 0; jj < 8; ++jj) t[c8 + jj][row] = p[jj];
    }
    __syncthreads();
#pragma unroll
    for (int i = 0; i < 2; ++i) {
        int chunk = threadIdx.x + i * 256;
        int d = chunk >> 3;
        int c8 = (chunk & 7) * 8;
        uint4 v = *(const uint4*)&t[d][c8];
        *(uint4*)&vt[((size_t)bh * HD + d) * S_LEN + s0 + c8] = v;
    }
}

// ---------------- Flash attention (causal), R14 ----------------
// grid (32, 16): x = bh (-> XCD = bh%8, K/V L2-local), y -> tA via
// pair-balanced remap (y<8 ? y : 23-y); tB = 31-tA. 256 thr = 4 waves.
// Wave w = (g = w&1, hv = w>>1): q-rows g*32..g*32+31 of BOTH tiles (2
// 16-row frags each), kv-half hv of every staged KV tile. LDS dbuf K/V,
// one barrier/iter, XOR bank swizzle. P redistributed S^T-frag -> A-frag
// in-register via v_permlane32/16_swap_b32. Wave pairs (w, w+2) merge
// (O, l) partials via LDS at the end (exp2-softmax -> associative).
__global__ __launch_bounds__(256, 2) void attn(const u16* __restrict__ qkv,
                                               const u16* __restrict__ vt,
                                               u16* __restrict__ e) {
    const int tid = threadIdx.x;
    const int w = tid >> 6, lane = tid & 63;
    const int quad = lane >> 4, lr = lane & 15;
    const int g = w & 1, hv = w >> 1;
    const int y = blockIdx.y;
    const int tA = (y < 8) ? y : 23 - y;  // pair-balanced: co-resident pair sums to 49 iters
    const int tB = 31 - tA;
    const int bh = blockIdx.x, b = bh >> 4, h = bh & 15;

    __shared__ alignas(16) u16 smem[17408];  // 34816 B (K/V 32768; epi 34304)
    u16* Ks = smem;           // 2 buf x [d-half][kv row 64][32] = 8192 u16
    u16* Vs = smem + 8192;    // 2 buf x [kv-half][d row 64][32] = 8192 u16

    const u16* qkv_b = qkv + (size_t)b * S_LEN * QKV_W;
    bf16x8 qfA[2][2], qfB[2][2];
    int qgA[2], qgB[2];
#pragma unroll
    for (int f = 0; f < 2; ++f) {
        const u16* qra = qkv_b + (size_t)(tA * 64 + g * 32 + f * 16 + lr) * QKV_W + h * HD + quad * 8;
        const u16* qrb = qkv_b + (size_t)(tB * 64 + g * 32 + f * 16 + lr) * QKV_W + h * HD + quad * 8;
        qfA[f][0] = *(const bf16x8*)qra;
        qfA[f][1] = *(const bf16x8*)(qra + 32);
        qfB[f][0] = *(const bf16x8*)qrb;
        qfB[f][1] = *(const bf16x8*)(qrb + 32);
        qgA[f] = tA * 64 + g * 32 + f * 16 + lr;
        qgB[f] = tB * 64 + g * 32 + f * 16 + lr;
    }

    const u16* kbase = qkv_b + EMB + h * HD;          // K[s][d], stride 3072
    const u16* vbase = vt + (size_t)bh * HD * S_LEN;  // V^T[d][s], stride 2048

    f32x4 oA[2][4] = {}, oB[2][4] = {};
    float lsA[2] = {0.f, 0.f}, lsB[2] = {0.f, 0.f};

    // staging: every wave stages 16 K-rows + 16 V-rows (4 gld_lds/thread).
    // LDS dest LINEAR in lane (gld_lds requirement); bank-swizzle applied by
    // permuting the GLOBAL source 16B chunk: slot (row,c') <- chunk c'^((row>>1)&3).
    const int sr = w * 16 + (lane >> 2);                     // dest row 0..63
    const int scl = (lane & 3) * 8;                          // dest chunk (linear)
    const int scg = ((lane & 3) ^ ((lane >> 3) & 3)) * 8;    // swizzled source chunk

    auto stage = [&](int j, int bb) {
        const int kv0 = j * 64;
        gld_lds16(kbase + (size_t)(kv0 + sr) * QKV_W + scg,
                  &Ks[bb * 4096 + sr * 32 + scl]);
        gld_lds16(kbase + (size_t)(kv0 + sr) * QKV_W + 32 + scg,
                  &Ks[bb * 4096 + 2048 + sr * 32 + scl]);
        gld_lds16(vbase + (size_t)sr * S_LEN + kv0 + scg,
                  &Vs[bb * 4096 + sr * 32 + scl]);
        gld_lds16(vbase + (size_t)sr * S_LEN + kv0 + 32 + scg,
                  &Vs[bb * 4096 + 2048 + sr * 32 + scl]);
    };

    // fragment-read chunk, swizzled: quad ^ ((row>>1)&3) with row ≡ lr mod 16
    const int xq8 = (quad ^ ((lr >> 1) & 3)) * 8;

    // exp2 (raw v_exp_f32) + mask + truncation-pack + permlane redistribution:
    // input s[2] (S^T frag: lane(quad,lr) has kv = kvh + nt*16 + quad*4 + r),
    // output bf16x8 A-frag for PV.
    auto softpack = [&](const f32x4* s, bool diag, int qg, int kvg,
                        float& lsum) -> bf16x8 {
        float p[8];
#pragma unroll
        for (int nt = 0; nt < 2; ++nt)
#pragma unroll
            for (int r = 0; r < 4; ++r) {
                float pv = __builtin_amdgcn_exp2f(s[nt][r]);
                if (diag) pv = (kvg + nt * 16 + quad * 4 + r > qg) ? 0.f : pv;
                p[nt * 4 + r] = pv;
            }
        lsum += ((p[0] + p[1]) + (p[2] + p[3])) + ((p[4] + p[5]) + (p[6] + p[7]));
        unsigned x0 = __builtin_amdgcn_perm(__float_as_uint(p[1]),
                                            __float_as_uint(p[0]), 0x07060302u);
        unsigned x1 = __builtin_amdgcn_perm(__float_as_uint(p[3]),
                                            __float_as_uint(p[2]), 0x07060302u);
        unsigned x2 = __builtin_amdgcn_perm(__float_as_uint(p[5]),
                                            __float_as_uint(p[4]), 0x07060302u);
        unsigned x3 = __builtin_amdgcn_perm(__float_as_uint(p[7]),
                                            __float_as_uint(p[6]), 0x07060302u);
        // (r0,r2) = swap16(swap32(x0,x2)); (r1,r3) = swap16(swap32(x1,x3))
        asm("v_permlane32_swap_b32 %0, %1" : "+v"(x0), "+v"(x2));
        asm("v_permlane16_swap_b32 %0, %1" : "+v"(x0), "+v"(x2));
        asm("v_permlane32_swap_b32 %0, %1" : "+v"(x1), "+v"(x3));
        asm("v_permlane16_swap_b32 %0, %1" : "+v"(x1), "+v"(x3));
        union { unsigned u[4]; bf16x8 v; } r;
        r.u[0] = x0; r.u[1] = x1; r.u[2] = x2; r.u[3] = x3;
        return r.v;
    };

    stage(0, 0);
    for (int j = 0; j <= tB; ++j) {
        const int bb = j & 1;
        __syncthreads();  // staged buf bb complete; other buf free
        if (j < tB) stage(j + 1, 1 - bb);
        const bool doA = (j <= tA);
        const u16* ks = &Ks[bb * 4096];
        const u16* vs = &Vs[bb * 4096];
        const int kvh = hv * 32;  // this wave's kv-half within the tile

        // ---- K fragments once; S^T for 2 tiles x 2 q-frags ----
        bf16x8 k0[2], k1[2];
#pragma unroll
        for (int nt = 0; nt < 2; ++nt) {
            const int kvr = kvh + nt * 16 + lr;
            k0[nt] = *(const bf16x8*)&ks[kvr * 32 + xq8];
            k1[nt] = *(const bf16x8*)&ks[2048 + kvr * 32 + xq8];
        }
        f32x4 sB[2][2], sA[2][2];
#pragma unroll
        for (int f = 0; f < 2; ++f)
#pragma unroll
            for (int nt = 0; nt < 2; ++nt) {
                f32x4 z = {};
                z = __builtin_amdgcn_mfma_f32_16x16x32_bf16(k0[nt], qfB[f][0], z, 0, 0, 0);
                z = __builtin_amdgcn_mfma_f32_16x16x32_bf16(k1[nt], qfB[f][1], z, 0, 0, 0);
                sB[f][nt] = z;
                if (doA) {
                    f32x4 za = {};
                    za = __builtin_amdgcn_mfma_f32_16x16x32_bf16(k0[nt], qfA[f][0], za, 0, 0, 0);
                    za = __builtin_amdgcn_mfma_f32_16x16x32_bf16(k1[nt], qfA[f][1], za, 0, 0, 0);
                    sA[f][nt] = za;
                }
            }

        // ---- softmax + in-register P redistribution ----
        const int kvg = j * 64 + kvh;
        bf16x8 pB[2], pA[2];
#pragma unroll
        for (int f = 0; f < 2; ++f)
            pB[f] = softpack(sB[f], j == tB, qgB[f], kvg, lsB[f]);
        if (doA)
#pragma unroll
            for (int f = 0; f < 2; ++f)
                pA[f] = softpack(sA[f], j == tA, qgA[f], kvg, lsA[f]);

        // ---- O += P @ V, shared V fragments across 4 q-frags ----
#pragma unroll
        for (int nt = 0; nt < 4; ++nt) {
            bf16x8 v = *(const bf16x8*)&vs[hv * 2048 + (nt * 16 + lr) * 32 + xq8];
#pragma unroll
            for (int f = 0; f < 2; ++f) {
                oB[f][nt] = __builtin_amdgcn_mfma_f32_16x16x32_bf16(pB[f], v, oB[f][nt], 0, 0, 0);
                if (doA)
                    oA[f][nt] = __builtin_amdgcn_mfma_f32_16x16x32_bf16(pA[f], v, oA[f][nt], 0, 0, 0);
            }
        }
    }

    // ---- merge wave-pair (kv-half) partials via LDS, finalize ----
    float lfA[2], lfB[2];
#pragma unroll
    for (int f = 0; f < 2; ++f) {
        lfA[f] = lsA[f] + __shfl_xor(lsA[f], 16, 64);
        lfA[f] += __shfl_xor(lfA[f], 32, 64);
        lfB[f] = lsB[f] + __shfl_xor(lsB[f], 16, 64);
        lfB[f] += __shfl_xor(lfB[f], 32, 64);
    }
    __syncthreads();  // all compute done; K/V LDS dead -> reuse
    float* mA = (float*)smem;       // [64][66] f32 tile-A partials
    float* mB = mA + 64 * 66;       // [64][66] f32 tile-B partials
    float* lAr = mB + 64 * 66;      // [64] row sums (tile A, half 1)
    float* lBr = lAr + 64;          // [64] row sums (tile B, half 0)
    if (hv) {
#pragma unroll
        for (int f = 0; f < 2; ++f) {
#pragma unroll
            for (int nt = 0; nt < 4; ++nt)
#pragma unroll
                for (int r = 0; r < 4; ++r)
                    mA[(g * 32 + f * 16 + quad * 4 + r) * 66 + nt * 16 + lr] = oA[f][nt][r];
            if (lane < 16) lAr[g * 32 + f * 16 + lane] = lfA[f];
        }
    } else {
#pragma unroll
        for (int f = 0; f < 2; ++f) {
#pragma unroll
            for (int nt = 0; nt < 4; ++nt)
#pragma unroll
                for (int r = 0; r < 4; ++r)
                    mB[(g * 32 + f * 16 + quad * 4 + r) * 66 + nt * 16 + lr] = oB[f][nt][r];
            if (lane < 16) lBr[g * 32 + f * 16 + lane] = lfB[f];
        }
    }
    __syncthreads();
    if (!hv) {  // hv==0 waves finalize tile A
#pragma unroll
        for (int f = 0; f < 2; ++f) {
            float lff = lfA[f] + lAr[g * 32 + f * 16 + lr];
#pragma unroll
            for (int r = 0; r < 4; ++r) {
                float inv = 1.0f / __shfl(lff, quad * 4 + r, 64);
                size_t row = (size_t)(b * S_LEN + tA * 64 + g * 32 + f * 16 + quad * 4 + r) * EMB + h * HD;
#pragma unroll
                for (int nt = 0; nt < 4; ++nt)
                    e[row + nt * 16 + lr] =
                        f2bf((oA[f][nt][r] + mA[(g * 32 + f * 16 + quad * 4 + r) * 66 + nt * 16 + lr]) * inv);
            }
        }
    } else {  // hv==1 waves finalize tile B
#pragma unroll
        for (int f = 0; f < 2; ++f) {
            float lff = lfB[f] + lBr[g * 32 + f * 16 + lr];
#pragma unroll
            for (int r = 0; r < 4; ++r) {
                float inv = 1.0f / __shfl(lff, quad * 4 + r, 64);
                size_t row = (size_t)(b * S_LEN + tB * 64 + g * 32 + f * 16 + quad * 4 + r) * EMB + h * HD;
#pragma unroll
                for (int nt = 0; nt < 4; ++nt)
                    e[row + nt * 16 + lr] =
                        f2bf((oB[f][nt][r] + mB[(g * 32 + f * 16 + quad * 4 + r) * 66 + nt * 16 + lr]) * inv);
            }
        }
    }
}

// ---------------- launcher ----------------
extern "C" void kernel_launch(void* const* d_in, const int* in_sizes, int n_in,
                              void* d_out, int out_size, void* d_ws, size_t ws_size,
                              hipStream_t stream) {
    const float* x = (const float*)d_in[0];
    const float* w_qkv = (const float*)d_in[1];
    const float* w0 = (const float*)d_in[2];
    float* out = (float*)d_out;

    const size_t M = (size_t)BATCH * S_LEN;  // 4096
    u16* xb = (u16*)d_ws;
    u16* wqb = xb + M * EMB;
    u16* w0b = wqb + (size_t)QKV_W * EMB;
    u16* qkvb = w0b + (size_t)EMB * EMB;
    u16* vtb = qkvb + M * QKV_W;
    u16* eb = vtb + (size_t)BATCH * NH * HD * S_LEN;

    cvt_all<<<(XN4 + WQ4 + W04) / 256, 256, 0, stream>>>(x, w_qkv, w0, xb, wqb, w0b);

    // qkv = x @ w_qkv^T; Q columns pre-scaled by CSC
    gemm_bt<u16, 128><<<dim3(QKV_W / 128, M / 128), 256, 0, stream>>>(
        xb, wqb, qkvb, (int)M, QKV_W, EMB, EMB);

    transpose_v<<<dim3(S_LEN / 64, BATCH * NH), 256, 0, stream>>>(qkvb, vtb);

    // grid x = bh so all pi-blocks of one head share an XCD (id%8 = bh%8)
    attn<<<dim3(BATCH * NH, 16), 256, 0, stream>>>(qkvb, vtb, eb);

    // out = e @ w0^T (128x128 tiles -> 256 blocks, 1/CU)
    gemm_bt<float, 128><<<dim3(EMB / 128, M / 128), 256, 0, stream>>>(
        eb, w0b, out, (int)M, EMB, EMB, 0);
}

// Round 8
// 187.557 us; speedup vs baseline: 1.0013x; 1.0013x over previous
//
#include <hip/hip_runtime.h>

// MultiHeadSelfAttention: B=2, S=2048, E=1024, H=16, D=64
// bf16 MFMA pipeline. R16 = R15 with the last-K-tile vmcnt race fixed:
//  (1) QKV GEMM: 256x256 8-wave 4-phase/K-tile kernel (T2 LDS XOR-swizzle +
//      T3/T4 counted-vmcnt pipeline + T5 setprio). Raw s_barrier at P0/P2;
//      vmcnt(2) at P0, vmcnt(4) at P2 -- except the FINAL tile where no
//      prefetch is in flight and P2 must drain to vmcnt(0) (R15 bug: the
//      vmcnt(4) no-op there let P2/P3 read LDS before AHm1 landed).
//  (2) out-projection GEMM: BN=64 / 512 blocks (R14's BN=128 regression
//      reverted).
//  attn unchanged from R14 (exp2 builtin + R13 skeleton).

typedef unsigned short u16;
typedef short bf16x8 __attribute__((ext_vector_type(8)));
typedef float f32x4 __attribute__((ext_vector_type(4)));
typedef unsigned short u16x4 __attribute__((ext_vector_type(4)));

#define S_LEN 2048
#define EMB 1024
#define NH 16
#define HD 64
#define QKV_W 3072
#define BATCH 2
#define CSC 0.18033688f  // 0.125 * log2(e)

static __device__ __forceinline__ u16 f2bf(float f) {
    unsigned x = __float_as_uint(f);
    return (u16)((x + 0x7fffu + ((x >> 16) & 1u)) >> 16);
}

static __device__ __forceinline__ void gld_lds16(const u16* g, u16* l) {
    __builtin_amdgcn_global_load_lds(
        (const __attribute__((address_space(1))) void*)g,
        (__attribute__((address_space(3))) void*)l, 16, 0, 0);
}

// ---------------- fused fp32 -> bf16 casts (3 ranges) ----------------
#define XN4 (BATCH * S_LEN * EMB / 4)      // 1048576
#define WQ4 (QKV_W * EMB / 4)              // 786432
#define W04 (EMB * EMB / 4)                // 262144
__global__ __launch_bounds__(256) void cvt_all(const float* __restrict__ x,
                                               const float* __restrict__ wq,
                                               const float* __restrict__ w0,
                                               u16* __restrict__ xb,
                                               u16* __restrict__ wqb,
                                               u16* __restrict__ w0b) {
    int i = blockIdx.x * 256 + threadIdx.x;
    const float* src;
    u16* dst;
    int off;
    if (i < XN4) { src = x; dst = xb; off = i; }
    else if (i < XN4 + WQ4) { src = wq; dst = wqb; off = i - XN4; }
    else { src = w0; dst = w0b; off = i - XN4 - WQ4; }
    float4 v = ((const float4*)src)[off];
    u16x4 o;
    o[0] = f2bf(v.x); o[1] = f2bf(v.y); o[2] = f2bf(v.z); o[3] = f2bf(v.w);
    ((u16x4*)dst)[off] = o;
}

// ---------------- GEMM 256x256 (8-phase style): C = A[M,K] @ Bt[N,K]^T ----
// 512 thr = 8 waves (2M x 4N). BK=64, dbuf LDS 128KB, XOR bank swizzle
// (slot = chunk ^ (row&7), applied to GLOBAL source; gld_lds dest linear).
// 4 phases per K-tile: (mh,kh) in {0,1}^2; 16 MFMA each; B-frags read at
// kh-first-use and held. Counted vmcnt: P0 vmcnt(2); P2 vmcnt(4) while
// prefetching, vmcnt(0) on the final tile. Raw s_barrier at P0/P2 only;
// stages of kt+1 spread one-half-per-phase in consumption order
// [BH0, BH1, AHm0, AHm1].
template <typename OutT>
__global__ __launch_bounds__(512, 1) void gemm256(const u16* __restrict__ A,
                                                  const u16* __restrict__ Bt,
                                                  OutT* __restrict__ C,
                                                  int M, int N, int K, int qcols) {
    __shared__ alignas(16) u16 Abuf[2][256 * 64];
    __shared__ alignas(16) u16 Bbuf[2][256 * 64];
    const int tid = threadIdx.x;
    const int lane = tid & 63;
    const int w = tid >> 6;
    const int quad = lane >> 4, lr = lane & 15;
    const int wave_m = w >> 2, wave_n = w & 3;
    const int m0 = blockIdx.y * 256, n0 = blockIdx.x * 256;
    const int NT = K >> 6;
    const float sc = (n0 < qcols) ? CSC : 1.0f;

    // A half mh: rows {mh*64..mh*64+63} U {128+mh*64..}, full 64-k per row.
    auto stageA = [&](int kt, int bb, int mh) {
#pragma unroll
        for (int i = 0; i < 2; ++i) {
            int c = tid + i * 512;            // 0..1023
            int rl = c >> 3, ch = c & 7;      // 128 rows x 8 chunks
            int row = (((rl & 64) << 1) | (rl & 63)) + (mh << 6);
            gld_lds16(&A[(size_t)(m0 + row) * K + kt * 64 + ((ch ^ (row & 7)) << 3)],
                      &Abuf[bb][row * 64 + ch * 8]);
        }
    };
    // B half nh: n-rows nh*128 .. +127, full 64-k per row.
    auto stageB = [&](int kt, int bb, int nh) {
#pragma unroll
        for (int i = 0; i < 2; ++i) {
            int c = tid + i * 512;
            int rl = c >> 3, ch = c & 7;
            int row = rl + (nh << 7);
            gld_lds16(&Bt[(size_t)(n0 + row) * K + kt * 64 + ((ch ^ (row & 7)) << 3)],
                      &Bbuf[bb][row * 64 + ch * 8]);
        }
    };

    f32x4 acc[8][4] = {};
    const int xs = lr & 7;  // row-derived swizzle bits for frag reads

    // prologue: stage K-tile 0 in consumption order
    stageB(0, 0, 0); stageB(0, 0, 1); stageA(0, 0, 0); stageA(0, 0, 1);

    for (int kt = 0; kt < NT; ++kt) {
        const int bb = kt & 1, nb = bb ^ 1;
        const bool pf = (kt + 1 < NT);
        bf16x8 bfr[2][4];

        // ---------- P0: (mh=0, kh=0) ----------
        asm volatile("s_waitcnt vmcnt(2)" ::: "memory");  // BH0,BH1,AHm0 of kt done
        __builtin_amdgcn_s_barrier();
        if (pf) stageB(kt + 1, nb, 0);
        {
            bf16x8 af[4];
#pragma unroll
            for (int mf = 0; mf < 4; ++mf) {
                int row = wave_m * 128 + mf * 16 + lr;
                af[mf] = *(const bf16x8*)&Abuf[bb][row * 64 + ((quad ^ xs) << 3)];
            }
#pragma unroll
            for (int nf = 0; nf < 4; ++nf) {
                int row = wave_n * 64 + nf * 16 + lr;
                bfr[0][nf] = *(const bf16x8*)&Bbuf[bb][row * 64 + ((quad ^ xs) << 3)];
            }
            __builtin_amdgcn_s_setprio(1);
#pragma unroll
            for (int mf = 0; mf < 4; ++mf)
#pragma unroll
                for (int nf = 0; nf < 4; ++nf)
                    acc[mf][nf] = __builtin_amdgcn_mfma_f32_16x16x32_bf16(
                        af[mf], bfr[0][nf], acc[mf][nf], 0, 0, 0);
            __builtin_amdgcn_s_setprio(0);
        }

        // ---------- P1: (mh=0, kh=1) ----------
        if (pf) stageB(kt + 1, nb, 1);
        {
            bf16x8 af[4];
#pragma unroll
            for (int mf = 0; mf < 4; ++mf) {
                int row = wave_m * 128 + mf * 16 + lr;
                af[mf] = *(const bf16x8*)&Abuf[bb][row * 64 + (((4 + quad) ^ xs) << 3)];
            }
#pragma unroll
            for (int nf = 0; nf < 4; ++nf) {
                int row = wave_n * 64 + nf * 16 + lr;
                bfr[1][nf] = *(const bf16x8*)&Bbuf[bb][row * 64 + (((4 + quad) ^ xs) << 3)];
            }
            __builtin_amdgcn_s_setprio(1);
#pragma unroll
            for (int mf = 0; mf < 4; ++mf)
#pragma unroll
                for (int nf = 0; nf < 4; ++nf)
                    acc[mf][nf] = __builtin_amdgcn_mfma_f32_16x16x32_bf16(
                        af[mf], bfr[1][nf], acc[mf][nf], 0, 0, 0);
            __builtin_amdgcn_s_setprio(0);
        }

        // ---------- P2: (mh=1, kh=0) ----------
        if (pf) {
            asm volatile("s_waitcnt vmcnt(4)" ::: "memory");  // AHm1 of kt done
        } else {
            asm volatile("s_waitcnt vmcnt(0)" ::: "memory");  // final tile: full drain
        }
        __builtin_amdgcn_s_barrier();
        if (pf) stageA(kt + 1, nb, 0);
        {
            bf16x8 af[4];
#pragma unroll
            for (int mf = 0; mf < 4; ++mf) {
                int row = wave_m * 128 + 64 + mf * 16 + lr;
                af[mf] = *(const bf16x8*)&Abuf[bb][row * 64 + ((quad ^ xs) << 3)];
            }
            __builtin_amdgcn_s_setprio(1);
#pragma unroll
            for (int mf = 0; mf < 4; ++mf)
#pragma unroll
                for (int nf = 0; nf < 4; ++nf)
                    acc[4 + mf][nf] = __builtin_amdgcn_mfma_f32_16x16x32_bf16(
                        af[mf], bfr[0][nf], acc[4 + mf][nf], 0, 0, 0);
            __builtin_amdgcn_s_setprio(0);
        }

        // ---------- P3: (mh=1, kh=1) ----------
        if (pf) stageA(kt + 1, nb, 1);
        {
            bf16x8 af[4];
#pragma unroll
            for (int mf = 0; mf < 4; ++mf) {
                int row = wave_m * 128 + 64 + mf * 16 + lr;
                af[mf] = *(const bf16x8*)&Abuf[bb][row * 64 + (((4 + quad) ^ xs) << 3)];
            }
            __builtin_amdgcn_s_setprio(1);
#pragma unroll
            for (int mf = 0; mf < 4; ++mf)
#pragma unroll
                for (int nf = 0; nf < 4; ++nf)
                    acc[4 + mf][nf] = __builtin_amdgcn_mfma_f32_16x16x32_bf16(
                        af[mf], bfr[1][nf], acc[4 + mf][nf], 0, 0, 0);
            __builtin_amdgcn_s_setprio(0);
        }
    }

    // ---------- epilogue ----------
#pragma unroll
    for (int mi = 0; mi < 8; ++mi) {
        int row0 = m0 + wave_m * 128 + (mi >> 2) * 64 + (mi & 3) * 16 + quad * 4;
#pragma unroll
        for (int r = 0; r < 4; ++r) {
#pragma unroll
            for (int nf = 0; nf < 4; ++nf) {
                int gc = n0 + wave_n * 64 + nf * 16 + lr;
                float v = acc[mi][nf][r] * sc;
                if constexpr (sizeof(OutT) == 2)
                    C[(size_t)(row0 + r) * N + gc] = (OutT)f2bf(v);
                else
                    C[(size_t)(row0 + r) * N + gc] = (OutT)v;
            }
        }
    }
}

// ---------------- GEMM: C[M,N] = A[M,K] @ Bt[N,K]^T (128-tile) ----------------
// BM=128, BN template, BK=32, 256 thr / 4 waves. Used for out-projection.
template <typename OutT, int BN>
__global__ __launch_bounds__(256) void gemm_bt(const u16* __restrict__ A,
                                               const u16* __restrict__ Bt,
                                               OutT* __restrict__ C,
                                               int M, int N, int K, int qcols) {
    constexpr int NF = BN / 32;  // n-frags per wave
    __shared__ alignas(16) u16 As[128 * 32];
    __shared__ alignas(16) u16 Bs[BN * 32];
    const int tid = threadIdx.x;
    const int wave = tid >> 6, lane = tid & 63;
    const int quad = lane >> 4, lr = lane & 15;
    const int m0 = blockIdx.y * 128, n0 = blockIdx.x * BN;
    const int wm = (wave & 1) * 64, wn = (wave >> 1) * (BN / 2);
    const float sc = (n0 < qcols) ? CSC : 1.0f;

    f32x4 acc[4][NF] = {};

    for (int k0 = 0; k0 < K; k0 += 32) {
#pragma unroll
        for (int i = 0; i < 2; ++i) {
            int chunk = tid + i * 256;
            int row = chunk >> 2;
            int col8 = (chunk & 3) * 8;
            gld_lds16(&A[(size_t)(m0 + row) * K + k0 + col8], &As[row * 32 + col8]);
        }
#pragma unroll
        for (int i = 0; i < BN / 64; ++i) {
            int chunk = tid + i * 256;
            int row = chunk >> 2;
            int col8 = (chunk & 3) * 8;
            gld_lds16(&Bt[(size_t)(n0 + row) * K + k0 + col8], &Bs[row * 32 + col8]);
        }
        __syncthreads();
        bf16x8 af[4], bf[NF];
#pragma unroll
        for (int i = 0; i < 4; ++i)
            af[i] = *(const bf16x8*)&As[(wm + i * 16 + lr) * 32 + quad * 8];
#pragma unroll
        for (int i = 0; i < NF; ++i)
            bf[i] = *(const bf16x8*)&Bs[(wn + i * 16 + lr) * 32 + quad * 8];
#pragma unroll
        for (int mi = 0; mi < 4; ++mi)
#pragma unroll
            for (int ni = 0; ni < NF; ++ni)
                acc[mi][ni] = __builtin_amdgcn_mfma_f32_16x16x32_bf16(
                    af[mi], bf[ni], acc[mi][ni], 0, 0, 0);
        __syncthreads();
    }

#pragma unroll
    for (int mi = 0; mi < 4; ++mi) {
#pragma unroll
        for (int r = 0; r < 4; ++r) {
            int gr = m0 + wm + mi * 16 + quad * 4 + r;
#pragma unroll
            for (int ni = 0; ni < NF; ++ni) {
                int gc = n0 + wn + ni * 16 + lr;
                float v = acc[mi][ni][r] * sc;
                if constexpr (sizeof(OutT) == 2)
                    C[(size_t)gr * N + gc] = (OutT)f2bf(v);
                else
                    C[(size_t)gr * N + gc] = (OutT)v;
            }
        }
    }
}

// ---------------- V transpose: qkv[.,2048+h*64+d] -> vt[bh][d][s] ----------------
__global__ __launch_bounds__(256) void transpose_v(const u16* __restrict__ qkv,
                                                   u16* __restrict__ vt) {
    __shared__ alignas(16) u16 t[64][72];
    const int s0 = blockIdx.x * 64;
    const int bh = blockIdx.y;
    const int b = bh >> 4, h = bh & 15;
#pragma unroll
    for (int i = 0; i < 2; ++i) {
        int chunk = threadIdx.x + i * 256;
        int row = chunk >> 3;
        int c8 = (chunk & 7) * 8;
        uint4 v = *(const uint4*)&qkv[(size_t)(b * S_LEN + s0 + row) * QKV_W +
                                      2 * EMB + h * HD + c8];
        const u16* p = (const u16*)&v;
#pragma unroll
        for (int jj = 0; jj < 8; ++jj) t[c8 + jj][row] = p[jj];
    }
    __syncthreads();
#pragma unroll
    for (int i = 0; i < 2; ++i) {
        int chunk = threadIdx.x + i * 256;
        int d = chunk >> 3;
        int c8 = (chunk & 7) * 8;
        uint4 v = *(const uint4*)&t[d][c8];
        *(uint4*)&vt[((size_t)bh * HD + d) * S_LEN + s0 + c8] = v;
    }
}

// ---------------- Flash attention (causal), R14 structure ----------------
__global__ __launch_bounds__(256, 2) void attn(const u16* __restrict__ qkv,
                                               const u16* __restrict__ vt,
                                               u16* __restrict__ e) {
    const int tid = threadIdx.x;
    const int w = tid >> 6, lane = tid & 63;
    const int quad = lane >> 4, lr = lane & 15;
    const int g = w & 1, hv = w >> 1;
    const int y = blockIdx.y;
    const int tA = (y < 8) ? y : 23 - y;  // pair-balanced: co-resident pair sums to 49 iters
    const int tB = 31 - tA;
    const int bh = blockIdx.x, b = bh >> 4, h = bh & 15;

    __shared__ alignas(16) u16 smem[17408];  // 34816 B (K/V 32768; epi 34304)
    u16* Ks = smem;           // 2 buf x [d-half][kv row 64][32] = 8192 u16
    u16* Vs = smem + 8192;    // 2 buf x [kv-half][d row 64][32] = 8192 u16

    const u16* qkv_b = qkv + (size_t)b * S_LEN * QKV_W;
    bf16x8 qfA[2][2], qfB[2][2];
    int qgA[2], qgB[2];
#pragma unroll
    for (int f = 0; f < 2; ++f) {
        const u16* qra = qkv_b + (size_t)(tA * 64 + g * 32 + f * 16 + lr) * QKV_W + h * HD + quad * 8;
        const u16* qrb = qkv_b + (size_t)(tB * 64 + g * 32 + f * 16 + lr) * QKV_W + h * HD + quad * 8;
        qfA[f][0] = *(const bf16x8*)qra;
        qfA[f][1] = *(const bf16x8*)(qra + 32);
        qfB[f][0] = *(const bf16x8*)qrb;
        qfB[f][1] = *(const bf16x8*)(qrb + 32);
        qgA[f] = tA * 64 + g * 32 + f * 16 + lr;
        qgB[f] = tB * 64 + g * 32 + f * 16 + lr;
    }

    const u16* kbase = qkv_b + EMB + h * HD;          // K[s][d], stride 3072
    const u16* vbase = vt + (size_t)bh * HD * S_LEN;  // V^T[d][s], stride 2048

    f32x4 oA[2][4] = {}, oB[2][4] = {};
    float lsA[2] = {0.f, 0.f}, lsB[2] = {0.f, 0.f};

    const int sr = w * 16 + (lane >> 2);                     // dest row 0..63
    const int scl = (lane & 3) * 8;                          // dest chunk (linear)
    const int scg = ((lane & 3) ^ ((lane >> 3) & 3)) * 8;    // swizzled source chunk

    auto stage = [&](int j, int bb) {
        const int kv0 = j * 64;
        gld_lds16(kbase + (size_t)(kv0 + sr) * QKV_W + scg,
                  &Ks[bb * 4096 + sr * 32 + scl]);
        gld_lds16(kbase + (size_t)(kv0 + sr) * QKV_W + 32 + scg,
                  &Ks[bb * 4096 + 2048 + sr * 32 + scl]);
        gld_lds16(vbase + (size_t)sr * S_LEN + kv0 + scg,
                  &Vs[bb * 4096 + sr * 32 + scl]);
        gld_lds16(vbase + (size_t)sr * S_LEN + kv0 + 32 + scg,
                  &Vs[bb * 4096 + 2048 + sr * 32 + scl]);
    };

    const int xq8 = (quad ^ ((lr >> 1) & 3)) * 8;

    auto softpack = [&](const f32x4* s, bool diag, int qg, int kvg,
                        float& lsum) -> bf16x8 {
        float p[8];
#pragma unroll
        for (int nt = 0; nt < 2; ++nt)
#pragma unroll
            for (int r = 0; r < 4; ++r) {
                float pv = __builtin_amdgcn_exp2f(s[nt][r]);
                if (diag) pv = (kvg + nt * 16 + quad * 4 + r > qg) ? 0.f : pv;
                p[nt * 4 + r] = pv;
            }
        lsum += ((p[0] + p[1]) + (p[2] + p[3])) + ((p[4] + p[5]) + (p[6] + p[7]));
        unsigned x0 = __builtin_amdgcn_perm(__float_as_uint(p[1]),
                                            __float_as_uint(p[0]), 0x07060302u);
        unsigned x1 = __builtin_amdgcn_perm(__float_as_uint(p[3]),
                                            __float_as_uint(p[2]), 0x07060302u);
        unsigned x2 = __builtin_amdgcn_perm(__float_as_uint(p[5]),
                                            __float_as_uint(p[4]), 0x07060302u);
        unsigned x3 = __builtin_amdgcn_perm(__float_as_uint(p[7]),
                                            __float_as_uint(p[6]), 0x07060302u);
        asm("v_permlane32_swap_b32 %0, %1" : "+v"(x0), "+v"(x2));
        asm("v_permlane16_swap_b32 %0, %1" : "+v"(x0), "+v"(x2));
        asm("v_permlane32_swap_b32 %0, %1" : "+v"(x1), "+v"(x3));
        asm("v_permlane16_swap_b32 %0, %1" : "+v"(x1), "+v"(x3));
        union { unsigned u[4]; bf16x8 v; } r;
        r.u[0] = x0; r.u[1] = x1; r.u[2] = x2; r.u[3] = x3;
        return r.v;
    };

    stage(0, 0);
    for (int j = 0; j <= tB; ++j) {
        const int bb = j & 1;
        __syncthreads();  // staged buf bb complete; other buf free
        if (j < tB) stage(j + 1, 1 - bb);
        const bool doA = (j <= tA);
        const u16* ks = &Ks[bb * 4096];
        const u16* vs = &Vs[bb * 4096];
        const int kvh = hv * 32;  // this wave's kv-half within the tile

        bf16x8 k0[2], k1[2];
#pragma unroll
        for (int nt = 0; nt < 2; ++nt) {
            const int kvr = kvh + nt * 16 + lr;
            k0[nt] = *(const bf16x8*)&ks[kvr * 32 + xq8];
            k1[nt] = *(const bf16x8*)&ks[2048 + kvr * 32 + xq8];
        }
        f32x4 sB[2][2], sA[2][2];
#pragma unroll
        for (int f = 0; f < 2; ++f)
#pragma unroll
            for (int nt = 0; nt < 2; ++nt) {
                f32x4 z = {};
                z = __builtin_amdgcn_mfma_f32_16x16x32_bf16(k0[nt], qfB[f][0], z, 0, 0, 0);
                z = __builtin_amdgcn_mfma_f32_16x16x32_bf16(k1[nt], qfB[f][1], z, 0, 0, 0);
                sB[f][nt] = z;
                if (doA) {
                    f32x4 za = {};
                    za = __builtin_amdgcn_mfma_f32_16x16x32_bf16(k0[nt], qfA[f][0], za, 0, 0, 0);
                    za = __builtin_amdgcn_mfma_f32_16x16x32_bf16(k1[nt], qfA[f][1], za, 0, 0, 0);
                    sA[f][nt] = za;
                }
            }

        const int kvg = j * 64 + kvh;
        bf16x8 pB[2], pA[2];
#pragma unroll
        for (int f = 0; f < 2; ++f)
            pB[f] = softpack(sB[f], j == tB, qgB[f], kvg, lsB[f]);
        if (doA)
#pragma unroll
            for (int f = 0; f < 2; ++f)
                pA[f] = softpack(sA[f], j == tA, qgA[f], kvg, lsA[f]);

#pragma unroll
        for (int nt = 0; nt < 4; ++nt) {
            bf16x8 v = *(const bf16x8*)&vs[hv * 2048 + (nt * 16 + lr) * 32 + xq8];
#pragma unroll
            for (int f = 0; f < 2; ++f) {
                oB[f][nt] = __builtin_amdgcn_mfma_f32_16x16x32_bf16(pB[f], v, oB[f][nt], 0, 0, 0);
                if (doA)
                    oA[f][nt] = __builtin_amdgcn_mfma_f32_16x16x32_bf16(pA[f], v, oA[f][nt], 0, 0, 0);
            }
        }
    }

    float lfA[2], lfB[2];
#pragma unroll
    for (int f = 0; f < 2; ++f) {
        lfA[f] = lsA[f] + __shfl_xor(lsA[f], 16, 64);
        lfA[f] += __shfl_xor(lfA[f], 32, 64);
        lfB[f] = lsB[f] + __shfl_xor(lsB[f], 16, 64);
        lfB[f] += __shfl_xor(lfB[f], 32, 64);
    }
    __syncthreads();  // all compute done; K/V LDS dead -> reuse
    float* mA = (float*)smem;       // [64][66] f32 tile-A partials
    float* mB = mA + 64 * 66;       // [64][66] f32 tile-B partials
    float* lAr = mB + 64 * 66;      // [64] row sums (tile A, half 1)
    float* lBr = lAr + 64;          // [64] row sums (tile B, half 0)
    if (hv) {
#pragma unroll
        for (int f = 0; f < 2; ++f) {
#pragma unroll
            for (int nt = 0; nt < 4; ++nt)
#pragma unroll
                for (int r = 0; r < 4; ++r)
                    mA[(g * 32 + f * 16 + quad * 4 + r) * 66 + nt * 16 + lr] = oA[f][nt][r];
            if (lane < 16) lAr[g * 32 + f * 16 + lane] = lfA[f];
        }
    } else {
#pragma unroll
        for (int f = 0; f < 2; ++f) {
#pragma unroll
            for (int nt = 0; nt < 4; ++nt)
#pragma unroll
                for (int r = 0; r < 4; ++r)
                    mB[(g * 32 + f * 16 + quad * 4 + r) * 66 + nt * 16 + lr] = oB[f][nt][r];
            if (lane < 16) lBr[g * 32 + f * 16 + lane] = lfB[f];
        }
    }
    __syncthreads();
    if (!hv) {  // hv==0 waves finalize tile A
#pragma unroll
        for (int f = 0; f < 2; ++f) {
            float lff = lfA[f] + lAr[g * 32 + f * 16 + lr];
#pragma unroll
            for (int r = 0; r < 4; ++r) {
                float inv = 1.0f / __shfl(lff, quad * 4 + r, 64);
                size_t row = (size_t)(b * S_LEN + tA * 64 + g * 32 + f * 16 + quad * 4 + r) * EMB + h * HD;
#pragma unroll
                for (int nt = 0; nt < 4; ++nt)
                    e[row + nt * 16 + lr] =
                        f2bf((oA[f][nt][r] + mA[(g * 32 + f * 16 + quad * 4 + r) * 66 + nt * 16 + lr]) * inv);
            }
        }
    } else {  // hv==1 waves finalize tile B
#pragma unroll
        for (int f = 0; f < 2; ++f) {
            float lff = lfB[f] + lBr[g * 32 + f * 16 + lr];
#pragma unroll
            for (int r = 0; r < 4; ++r) {
                float inv = 1.0f / __shfl(lff, quad * 4 + r, 64);
                size_t row = (size_t)(b * S_LEN + tB * 64 + g * 32 + f * 16 + quad * 4 + r) * EMB + h * HD;
#pragma unroll
                for (int nt = 0; nt < 4; ++nt)
                    e[row + nt * 16 + lr] =
                        f2bf((oB[f][nt][r] + mB[(g * 32 + f * 16 + quad * 4 + r) * 66 + nt * 16 + lr]) * inv);
            }
        }
    }
}

// ---------------- launcher ----------------
extern "C" void kernel_launch(void* const* d_in, const int* in_sizes, int n_in,
                              void* d_out, int out_size, void* d_ws, size_t ws_size,
                              hipStream_t stream) {
    const float* x = (const float*)d_in[0];
    const float* w_qkv = (const float*)d_in[1];
    const float* w0 = (const float*)d_in[2];
    float* out = (float*)d_out;

    const size_t M = (size_t)BATCH * S_LEN;  // 4096
    u16* xb = (u16*)d_ws;
    u16* wqb = xb + M * EMB;
    u16* w0b = wqb + (size_t)QKV_W * EMB;
    u16* qkvb = w0b + (size_t)EMB * EMB;
    u16* vtb = qkvb + M * QKV_W;
    u16* eb = vtb + (size_t)BATCH * NH * HD * S_LEN;

    cvt_all<<<(XN4 + WQ4 + W04) / 256, 256, 0, stream>>>(x, w_qkv, w0, xb, wqb, w0b);

    // qkv = x @ w_qkv^T; Q columns pre-scaled by CSC (256^2 4-phase kernel)
    gemm256<u16><<<dim3(QKV_W / 256, M / 256), 512, 0, stream>>>(
        xb, wqb, qkvb, (int)M, QKV_W, EMB, EMB);

    transpose_v<<<dim3(S_LEN / 64, BATCH * NH), 256, 0, stream>>>(qkvb, vtb);

    // grid x = bh so all pi-blocks of one head share an XCD (id%8 = bh%8)
    attn<<<dim3(BATCH * NH, 16), 256, 0, stream>>>(qkvb, vtb, eb);

    // out = e @ w0^T (128x64 tiles -> 512 blocks, 2/CU)
    gemm_bt<float, 64><<<dim3(EMB / 64, M / 128), 256, 0, stream>>>(
        eb, w0b, out, (int)M, EMB, EMB, 0);
}

// Round 9
// 173.061 us; speedup vs baseline: 1.0852x; 1.0838x over previous
//
#include <hip/hip_runtime.h>

// MultiHeadSelfAttention: B=2, S=2048, E=1024, H=16, D=64
// bf16 MFMA pipeline. R17: drop gemm256 (192-block grid + exposed ds_read
// chain = 533 TF, slower than 2-phase). Instead fix the REAL gemm_bt wall:
// its fragment reads were an 8-way LDS bank conflict (16-lane group -> 2
// bank-groups; 3.1M conflicts = LDS pipe 100% busy serializing). Apply
// R10's proven XOR swizzle (same 64B-row geometry as attn K/V tiles):
// source chunk ^= (row>>1)&3 staged via pre-swizzled global address
// (gld_lds dest linear), fragment read chunk = quad ^ ((lr>>1)&3).
// 2-way residual = free. Both gemm_bt instances (qkv + out) get it.
// attn unchanged from R14 (exp2 builtin + R13 skeleton).

typedef unsigned short u16;
typedef short bf16x8 __attribute__((ext_vector_type(8)));
typedef float f32x4 __attribute__((ext_vector_type(4)));
typedef unsigned short u16x4 __attribute__((ext_vector_type(4)));

#define S_LEN 2048
#define EMB 1024
#define NH 16
#define HD 64
#define QKV_W 3072
#define BATCH 2
#define CSC 0.18033688f  // 0.125 * log2(e)

static __device__ __forceinline__ u16 f2bf(float f) {
    unsigned x = __float_as_uint(f);
    return (u16)((x + 0x7fffu + ((x >> 16) & 1u)) >> 16);
}

static __device__ __forceinline__ void gld_lds16(const u16* g, u16* l) {
    __builtin_amdgcn_global_load_lds(
        (const __attribute__((address_space(1))) void*)g,
        (__attribute__((address_space(3))) void*)l, 16, 0, 0);
}

// ---------------- fused fp32 -> bf16 casts (3 ranges) ----------------
#define XN4 (BATCH * S_LEN * EMB / 4)      // 1048576
#define WQ4 (QKV_W * EMB / 4)              // 786432
#define W04 (EMB * EMB / 4)                // 262144
__global__ __launch_bounds__(256) void cvt_all(const float* __restrict__ x,
                                               const float* __restrict__ wq,
                                               const float* __restrict__ w0,
                                               u16* __restrict__ xb,
                                               u16* __restrict__ wqb,
                                               u16* __restrict__ w0b) {
    int i = blockIdx.x * 256 + threadIdx.x;
    const float* src;
    u16* dst;
    int off;
    if (i < XN4) { src = x; dst = xb; off = i; }
    else if (i < XN4 + WQ4) { src = wq; dst = wqb; off = i - XN4; }
    else { src = w0; dst = w0b; off = i - XN4 - WQ4; }
    float4 v = ((const float4*)src)[off];
    u16x4 o;
    o[0] = f2bf(v.x); o[1] = f2bf(v.y); o[2] = f2bf(v.z); o[3] = f2bf(v.w);
    ((u16x4*)dst)[off] = o;
}

// ---------------- GEMM: C[M,N] = A[M,K] @ Bt[N,K]^T (128-tile) ----------------
// BM=128, BN template (128 or 64), BK=32, 256 thr / 4 waves.
// Columns n < qcols scaled by CSC (Q pre-scaling for attention).
// LDS tiles XOR-bank-swizzled: slot (row, c') holds global chunk
// c' ^ ((row>>1)&3); fragment reads at chunk quad ^ ((lr>>1)&3).
// (8-way conflict -> 2-way, which is free; conflicts were 3.1M/dispatch.)
template <typename OutT, int BN>
__global__ __launch_bounds__(256) void gemm_bt(const u16* __restrict__ A,
                                               const u16* __restrict__ Bt,
                                               OutT* __restrict__ C,
                                               int M, int N, int K, int qcols) {
    constexpr int NF = BN / 32;  // n-frags per wave
    __shared__ alignas(16) u16 As[128 * 32];
    __shared__ alignas(16) u16 Bs[BN * 32];
    const int tid = threadIdx.x;
    const int wave = tid >> 6, lane = tid & 63;
    const int quad = lane >> 4, lr = lane & 15;
    const int m0 = blockIdx.y * 128, n0 = blockIdx.x * BN;
    const int wm = (wave & 1) * 64, wn = (wave >> 1) * (BN / 2);
    const float sc = (n0 < qcols) ? CSC : 1.0f;

    f32x4 acc[4][NF] = {};
    // fragment-read chunk, swizzled; (wm|wn|i*16)>>1 ≡ 0 mod 4 so the key
    // reduces to (lr>>1)&3 for every fragment row.
    const int xq8 = (quad ^ ((lr >> 1) & 3)) * 8;

    for (int k0 = 0; k0 < K; k0 += 32) {
#pragma unroll
        for (int i = 0; i < 2; ++i) {
            int chunk = tid + i * 256;
            int row = chunk >> 2;
            int dst8 = (chunk & 3) * 8;
            int src8 = (((chunk & 3) ^ ((chunk >> 3) & 3))) * 8;  // ^ (row>>1)&3
            gld_lds16(&A[(size_t)(m0 + row) * K + k0 + src8], &As[row * 32 + dst8]);
        }
#pragma unroll
        for (int i = 0; i < BN / 64; ++i) {
            int chunk = tid + i * 256;
            int row = chunk >> 2;
            int dst8 = (chunk & 3) * 8;
            int src8 = (((chunk & 3) ^ ((chunk >> 3) & 3))) * 8;
            gld_lds16(&Bt[(size_t)(n0 + row) * K + k0 + src8], &Bs[row * 32 + dst8]);
        }
        __syncthreads();
        bf16x8 af[4], bf[NF];
#pragma unroll
        for (int i = 0; i < 4; ++i)
            af[i] = *(const bf16x8*)&As[(wm + i * 16 + lr) * 32 + xq8];
#pragma unroll
        for (int i = 0; i < NF; ++i)
            bf[i] = *(const bf16x8*)&Bs[(wn + i * 16 + lr) * 32 + xq8];
#pragma unroll
        for (int mi = 0; mi < 4; ++mi)
#pragma unroll
            for (int ni = 0; ni < NF; ++ni)
                acc[mi][ni] = __builtin_amdgcn_mfma_f32_16x16x32_bf16(
                    af[mi], bf[ni], acc[mi][ni], 0, 0, 0);
        __syncthreads();
    }

#pragma unroll
    for (int mi = 0; mi < 4; ++mi) {
#pragma unroll
        for (int r = 0; r < 4; ++r) {
            int gr = m0 + wm + mi * 16 + quad * 4 + r;
#pragma unroll
            for (int ni = 0; ni < NF; ++ni) {
                int gc = n0 + wn + ni * 16 + lr;
                float v = acc[mi][ni][r] * sc;
                if constexpr (sizeof(OutT) == 2)
                    C[(size_t)gr * N + gc] = (OutT)f2bf(v);
                else
                    C[(size_t)gr * N + gc] = (OutT)v;
            }
        }
    }
}

// ---------------- V transpose: qkv[.,2048+h*64+d] -> vt[bh][d][s] ----------------
__global__ __launch_bounds__(256) void transpose_v(const u16* __restrict__ qkv,
                                                   u16* __restrict__ vt) {
    __shared__ alignas(16) u16 t[64][72];
    const int s0 = blockIdx.x * 64;
    const int bh = blockIdx.y;
    const int b = bh >> 4, h = bh & 15;
#pragma unroll
    for (int i = 0; i < 2; ++i) {
        int chunk = threadIdx.x + i * 256;
        int row = chunk >> 3;
        int c8 = (chunk & 7) * 8;
        uint4 v = *(const uint4*)&qkv[(size_t)(b * S_LEN + s0 + row) * QKV_W +
                                      2 * EMB + h * HD + c8];
        const u16* p = (const u16*)&v;
#pragma unroll
        for (int jj = 0; jj < 8; ++jj) t[c8 + jj][row] = p[jj];
    }
    __syncthreads();
#pragma unroll
    for (int i = 0; i < 2; ++i) {
        int chunk = threadIdx.x + i * 256;
        int d = chunk >> 3;
        int c8 = (chunk & 7) * 8;
        uint4 v = *(const uint4*)&t[d][c8];
        *(uint4*)&vt[((size_t)bh * HD + d) * S_LEN + s0 + c8] = v;
    }
}

// ---------------- Flash attention (causal), R14 structure ----------------
__global__ __launch_bounds__(256, 2) void attn(const u16* __restrict__ qkv,
                                               const u16* __restrict__ vt,
                                               u16* __restrict__ e) {
    const int tid = threadIdx.x;
    const int w = tid >> 6, lane = tid & 63;
    const int quad = lane >> 4, lr = lane & 15;
    const int g = w & 1, hv = w >> 1;
    const int y = blockIdx.y;
    const int tA = (y < 8) ? y : 23 - y;  // pair-balanced: co-resident pair sums to 49 iters
    const int tB = 31 - tA;
    const int bh = blockIdx.x, b = bh >> 4, h = bh & 15;

    __shared__ alignas(16) u16 smem[17408];  // 34816 B (K/V 32768; epi 34304)
    u16* Ks = smem;           // 2 buf x [d-half][kv row 64][32] = 8192 u16
    u16* Vs = smem + 8192;    // 2 buf x [kv-half][d row 64][32] = 8192 u16

    const u16* qkv_b = qkv + (size_t)b * S_LEN * QKV_W;
    bf16x8 qfA[2][2], qfB[2][2];
    int qgA[2], qgB[2];
#pragma unroll
    for (int f = 0; f < 2; ++f) {
        const u16* qra = qkv_b + (size_t)(tA * 64 + g * 32 + f * 16 + lr) * QKV_W + h * HD + quad * 8;
        const u16* qrb = qkv_b + (size_t)(tB * 64 + g * 32 + f * 16 + lr) * QKV_W + h * HD + quad * 8;
        qfA[f][0] = *(const bf16x8*)qra;
        qfA[f][1] = *(const bf16x8*)(qra + 32);
        qfB[f][0] = *(const bf16x8*)qrb;
        qfB[f][1] = *(const bf16x8*)(qrb + 32);
        qgA[f] = tA * 64 + g * 32 + f * 16 + lr;
        qgB[f] = tB * 64 + g * 32 + f * 16 + lr;
    }

    const u16* kbase = qkv_b + EMB + h * HD;          // K[s][d], stride 3072
    const u16* vbase = vt + (size_t)bh * HD * S_LEN;  // V^T[d][s], stride 2048

    f32x4 oA[2][4] = {}, oB[2][4] = {};
    float lsA[2] = {0.f, 0.f}, lsB[2] = {0.f, 0.f};

    const int sr = w * 16 + (lane >> 2);                     // dest row 0..63
    const int scl = (lane & 3) * 8;                          // dest chunk (linear)
    const int scg = ((lane & 3) ^ ((lane >> 3) & 3)) * 8;    // swizzled source chunk

    auto stage = [&](int j, int bb) {
        const int kv0 = j * 64;
        gld_lds16(kbase + (size_t)(kv0 + sr) * QKV_W + scg,
                  &Ks[bb * 4096 + sr * 32 + scl]);
        gld_lds16(kbase + (size_t)(kv0 + sr) * QKV_W + 32 + scg,
                  &Ks[bb * 4096 + 2048 + sr * 32 + scl]);
        gld_lds16(vbase + (size_t)sr * S_LEN + kv0 + scg,
                  &Vs[bb * 4096 + sr * 32 + scl]);
        gld_lds16(vbase + (size_t)sr * S_LEN + kv0 + 32 + scg,
                  &Vs[bb * 4096 + 2048 + sr * 32 + scl]);
    };

    const int xq8 = (quad ^ ((lr >> 1) & 3)) * 8;

    auto softpack = [&](const f32x4* s, bool diag, int qg, int kvg,
                        float& lsum) -> bf16x8 {
        float p[8];
#pragma unroll
        for (int nt = 0; nt < 2; ++nt)
#pragma unroll
            for (int r = 0; r < 4; ++r) {
                float pv = __builtin_amdgcn_exp2f(s[nt][r]);
                if (diag) pv = (kvg + nt * 16 + quad * 4 + r > qg) ? 0.f : pv;
                p[nt * 4 + r] = pv;
            }
        lsum += ((p[0] + p[1]) + (p[2] + p[3])) + ((p[4] + p[5]) + (p[6] + p[7]));
        unsigned x0 = __builtin_amdgcn_perm(__float_as_uint(p[1]),
                                            __float_as_uint(p[0]), 0x07060302u);
        unsigned x1 = __builtin_amdgcn_perm(__float_as_uint(p[3]),
                                            __float_as_uint(p[2]), 0x07060302u);
        unsigned x2 = __builtin_amdgcn_perm(__float_as_uint(p[5]),
                                            __float_as_uint(p[4]), 0x07060302u);
        unsigned x3 = __builtin_amdgcn_perm(__float_as_uint(p[7]),
                                            __float_as_uint(p[6]), 0x07060302u);
        asm("v_permlane32_swap_b32 %0, %1" : "+v"(x0), "+v"(x2));
        asm("v_permlane16_swap_b32 %0, %1" : "+v"(x0), "+v"(x2));
        asm("v_permlane32_swap_b32 %0, %1" : "+v"(x1), "+v"(x3));
        asm("v_permlane16_swap_b32 %0, %1" : "+v"(x1), "+v"(x3));
        union { unsigned u[4]; bf16x8 v; } r;
        r.u[0] = x0; r.u[1] = x1; r.u[2] = x2; r.u[3] = x3;
        return r.v;
    };

    stage(0, 0);
    for (int j = 0; j <= tB; ++j) {
        const int bb = j & 1;
        __syncthreads();  // staged buf bb complete; other buf free
        if (j < tB) stage(j + 1, 1 - bb);
        const bool doA = (j <= tA);
        const u16* ks = &Ks[bb * 4096];
        const u16* vs = &Vs[bb * 4096];
        const int kvh = hv * 32;  // this wave's kv-half within the tile

        bf16x8 k0[2], k1[2];
#pragma unroll
        for (int nt = 0; nt < 2; ++nt) {
            const int kvr = kvh + nt * 16 + lr;
            k0[nt] = *(const bf16x8*)&ks[kvr * 32 + xq8];
            k1[nt] = *(const bf16x8*)&ks[2048 + kvr * 32 + xq8];
        }
        f32x4 sB[2][2], sA[2][2];
#pragma unroll
        for (int f = 0; f < 2; ++f)
#pragma unroll
            for (int nt = 0; nt < 2; ++nt) {
                f32x4 z = {};
                z = __builtin_amdgcn_mfma_f32_16x16x32_bf16(k0[nt], qfB[f][0], z, 0, 0, 0);
                z = __builtin_amdgcn_mfma_f32_16x16x32_bf16(k1[nt], qfB[f][1], z, 0, 0, 0);
                sB[f][nt] = z;
                if (doA) {
                    f32x4 za = {};
                    za = __builtin_amdgcn_mfma_f32_16x16x32_bf16(k0[nt], qfA[f][0], za, 0, 0, 0);
                    za = __builtin_amdgcn_mfma_f32_16x16x32_bf16(k1[nt], qfA[f][1], za, 0, 0, 0);
                    sA[f][nt] = za;
                }
            }

        const int kvg = j * 64 + kvh;
        bf16x8 pB[2], pA[2];
#pragma unroll
        for (int f = 0; f < 2; ++f)
            pB[f] = softpack(sB[f], j == tB, qgB[f], kvg, lsB[f]);
        if (doA)
#pragma unroll
            for (int f = 0; f < 2; ++f)
                pA[f] = softpack(sA[f], j == tA, qgA[f], kvg, lsA[f]);

#pragma unroll
        for (int nt = 0; nt < 4; ++nt) {
            bf16x8 v = *(const bf16x8*)&vs[hv * 2048 + (nt * 16 + lr) * 32 + xq8];
#pragma unroll
            for (int f = 0; f < 2; ++f) {
                oB[f][nt] = __builtin_amdgcn_mfma_f32_16x16x32_bf16(pB[f], v, oB[f][nt], 0, 0, 0);
                if (doA)
                    oA[f][nt] = __builtin_amdgcn_mfma_f32_16x16x32_bf16(pA[f], v, oA[f][nt], 0, 0, 0);
            }
        }
    }

    float lfA[2], lfB[2];
#pragma unroll
    for (int f = 0; f < 2; ++f) {
        lfA[f] = lsA[f] + __shfl_xor(lsA[f], 16, 64);
        lfA[f] += __shfl_xor(lfA[f], 32, 64);
        lfB[f] = lsB[f] + __shfl_xor(lsB[f], 16, 64);
        lfB[f] += __shfl_xor(lfB[f], 32, 64);
    }
    __syncthreads();  // all compute done; K/V LDS dead -> reuse
    float* mA = (float*)smem;       // [64][66] f32 tile-A partials
    float* mB = mA + 64 * 66;       // [64][66] f32 tile-B partials
    float* lAr = mB + 64 * 66;      // [64] row sums (tile A, half 1)
    float* lBr = lAr + 64;          // [64] row sums (tile B, half 0)
    if (hv) {
#pragma unroll
        for (int f = 0; f < 2; ++f) {
#pragma unroll
            for (int nt = 0; nt < 4; ++nt)
#pragma unroll
                for (int r = 0; r < 4; ++r)
                    mA[(g * 32 + f * 16 + quad * 4 + r) * 66 + nt * 16 + lr] = oA[f][nt][r];
            if (lane < 16) lAr[g * 32 + f * 16 + lane] = lfA[f];
        }
    } else {
#pragma unroll
        for (int f = 0; f < 2; ++f) {
#pragma unroll
            for (int nt = 0; nt < 4; ++nt)
#pragma unroll
                for (int r = 0; r < 4; ++r)
                    mB[(g * 32 + f * 16 + quad * 4 + r) * 66 + nt * 16 + lr] = oB[f][nt][r];
            if (lane < 16) lBr[g * 32 + f * 16 + lane] = lfB[f];
        }
    }
    __syncthreads();
    if (!hv) {  // hv==0 waves finalize tile A
#pragma unroll
        for (int f = 0; f < 2; ++f) {
            float lff = lfA[f] + lAr[g * 32 + f * 16 + lr];
#pragma unroll
            for (int r = 0; r < 4; ++r) {
                float inv = 1.0f / __shfl(lff, quad * 4 + r, 64);
                size_t row = (size_t)(b * S_LEN + tA * 64 + g * 32 + f * 16 + quad * 4 + r) * EMB + h * HD;
#pragma unroll
                for (int nt = 0; nt < 4; ++nt)
                    e[row + nt * 16 + lr] =
                        f2bf((oA[f][nt][r] + mA[(g * 32 + f * 16 + quad * 4 + r) * 66 + nt * 16 + lr]) * inv);
            }
        }
    } else {  // hv==1 waves finalize tile B
#pragma unroll
        for (int f = 0; f < 2; ++f) {
            float lff = lfB[f] + lBr[g * 32 + f * 16 + lr];
#pragma unroll
            for (int r = 0; r < 4; ++r) {
                float inv = 1.0f / __shfl(lff, quad * 4 + r, 64);
                size_t row = (size_t)(b * S_LEN + tB * 64 + g * 32 + f * 16 + quad * 4 + r) * EMB + h * HD;
#pragma unroll
                for (int nt = 0; nt < 4; ++nt)
                    e[row + nt * 16 + lr] =
                        f2bf((oB[f][nt][r] + mB[(g * 32 + f * 16 + quad * 4 + r) * 66 + nt * 16 + lr]) * inv);
            }
        }
    }
}

// ---------------- launcher ----------------
extern "C" void kernel_launch(void* const* d_in, const int* in_sizes, int n_in,
                              void* d_out, int out_size, void* d_ws, size_t ws_size,
                              hipStream_t stream) {
    const float* x = (const float*)d_in[0];
    const float* w_qkv = (const float*)d_in[1];
    const float* w0 = (const float*)d_in[2];
    float* out = (float*)d_out;

    const size_t M = (size_t)BATCH * S_LEN;  // 4096
    u16* xb = (u16*)d_ws;
    u16* wqb = xb + M * EMB;
    u16* w0b = wqb + (size_t)QKV_W * EMB;
    u16* qkvb = w0b + (size_t)EMB * EMB;
    u16* vtb = qkvb + M * QKV_W;
    u16* eb = vtb + (size_t)BATCH * NH * HD * S_LEN;

    cvt_all<<<(XN4 + WQ4 + W04) / 256, 256, 0, stream>>>(x, w_qkv, w0, xb, wqb, w0b);

    // qkv = x @ w_qkv^T; Q columns pre-scaled by CSC (swizzled 128-tile)
    gemm_bt<u16, 128><<<dim3(QKV_W / 128, M / 128), 256, 0, stream>>>(
        xb, wqb, qkvb, (int)M, QKV_W, EMB, EMB);

    transpose_v<<<dim3(S_LEN / 64, BATCH * NH), 256, 0, stream>>>(qkvb, vtb);

    // grid x = bh so all pi-blocks of one head share an XCD (id%8 = bh%8)
    attn<<<dim3(BATCH * NH, 16), 256, 0, stream>>>(qkvb, vtb, eb);

    // out = e @ w0^T (128x64 tiles -> 512 blocks, 2/CU, swizzled)
    gemm_bt<float, 64><<<dim3(EMB / 64, M / 128), 256, 0, stream>>>(
        eb, w0b, out, (int)M, EMB, EMB, 0);
}

// Round 10
// 171.870 us; speedup vs baseline: 1.0927x; 1.0069x over previous
//
#include <hip/hip_runtime.h>

// MultiHeadSelfAttention: B=2, S=2048, E=1024, H=16, D=64
// bf16 MFMA pipeline. R18 = R17 + two measured-prior tweaks:
//  (1) T1 XCD-locality in both gemm_bt launches: grid swapped so
//      blockIdx.x = m-tile -> linear id = m + Dx*n -> XCD = m%8: all blocks
//      sharing an A-panel (256KB, re-read 24x/16x) hit one XCD's L2.
//      (Same mechanism that cut attn FETCH 66->12 MB in R11.)
//  (2) T5 s_setprio(1) around attn's QK and PV MFMA clusters: 2 desynced
//      blocks/CU -> MFMA waves preempt the other block's softmax VALU.
//  Everything else identical to R17.

typedef unsigned short u16;
typedef short bf16x8 __attribute__((ext_vector_type(8)));
typedef float f32x4 __attribute__((ext_vector_type(4)));
typedef unsigned short u16x4 __attribute__((ext_vector_type(4)));

#define S_LEN 2048
#define EMB 1024
#define NH 16
#define HD 64
#define QKV_W 3072
#define BATCH 2
#define CSC 0.18033688f  // 0.125 * log2(e)

static __device__ __forceinline__ u16 f2bf(float f) {
    unsigned x = __float_as_uint(f);
    return (u16)((x + 0x7fffu + ((x >> 16) & 1u)) >> 16);
}

static __device__ __forceinline__ void gld_lds16(const u16* g, u16* l) {
    __builtin_amdgcn_global_load_lds(
        (const __attribute__((address_space(1))) void*)g,
        (__attribute__((address_space(3))) void*)l, 16, 0, 0);
}

// ---------------- fused fp32 -> bf16 casts (3 ranges) ----------------
#define XN4 (BATCH * S_LEN * EMB / 4)      // 1048576
#define WQ4 (QKV_W * EMB / 4)              // 786432
#define W04 (EMB * EMB / 4)                // 262144
__global__ __launch_bounds__(256) void cvt_all(const float* __restrict__ x,
                                               const float* __restrict__ wq,
                                               const float* __restrict__ w0,
                                               u16* __restrict__ xb,
                                               u16* __restrict__ wqb,
                                               u16* __restrict__ w0b) {
    int i = blockIdx.x * 256 + threadIdx.x;
    const float* src;
    u16* dst;
    int off;
    if (i < XN4) { src = x; dst = xb; off = i; }
    else if (i < XN4 + WQ4) { src = wq; dst = wqb; off = i - XN4; }
    else { src = w0; dst = w0b; off = i - XN4 - WQ4; }
    float4 v = ((const float4*)src)[off];
    u16x4 o;
    o[0] = f2bf(v.x); o[1] = f2bf(v.y); o[2] = f2bf(v.z); o[3] = f2bf(v.w);
    ((u16x4*)dst)[off] = o;
}

// ---------------- GEMM: C[M,N] = A[M,K] @ Bt[N,K]^T (128-tile) ----------------
// BM=128, BN template (128 or 64), BK=32, 256 thr / 4 waves.
// GRID: blockIdx.x = m-tile (XCD = m%8 -> A-panel L2-local), blockIdx.y = n-tile.
// Columns n < qcols scaled by CSC (Q pre-scaling for attention).
// LDS tiles XOR-bank-swizzled: slot (row, c') holds global chunk
// c' ^ ((row>>1)&3); fragment reads at chunk quad ^ ((lr>>1)&3).
template <typename OutT, int BN>
__global__ __launch_bounds__(256) void gemm_bt(const u16* __restrict__ A,
                                               const u16* __restrict__ Bt,
                                               OutT* __restrict__ C,
                                               int M, int N, int K, int qcols) {
    constexpr int NF = BN / 32;  // n-frags per wave
    __shared__ alignas(16) u16 As[128 * 32];
    __shared__ alignas(16) u16 Bs[BN * 32];
    const int tid = threadIdx.x;
    const int wave = tid >> 6, lane = tid & 63;
    const int quad = lane >> 4, lr = lane & 15;
    const int m0 = blockIdx.x * 128, n0 = blockIdx.y * BN;  // x = m-tile (XCD-local A)
    const int wm = (wave & 1) * 64, wn = (wave >> 1) * (BN / 2);
    const float sc = (n0 < qcols) ? CSC : 1.0f;

    f32x4 acc[4][NF] = {};
    // fragment-read chunk, swizzled; (wm|wn|i*16)>>1 ≡ 0 mod 4 so the key
    // reduces to (lr>>1)&3 for every fragment row.
    const int xq8 = (quad ^ ((lr >> 1) & 3)) * 8;

    for (int k0 = 0; k0 < K; k0 += 32) {
#pragma unroll
        for (int i = 0; i < 2; ++i) {
            int chunk = tid + i * 256;
            int row = chunk >> 2;
            int dst8 = (chunk & 3) * 8;
            int src8 = (((chunk & 3) ^ ((chunk >> 3) & 3))) * 8;  // ^ (row>>1)&3
            gld_lds16(&A[(size_t)(m0 + row) * K + k0 + src8], &As[row * 32 + dst8]);
        }
#pragma unroll
        for (int i = 0; i < BN / 64; ++i) {
            int chunk = tid + i * 256;
            int row = chunk >> 2;
            int dst8 = (chunk & 3) * 8;
            int src8 = (((chunk & 3) ^ ((chunk >> 3) & 3))) * 8;
            gld_lds16(&Bt[(size_t)(n0 + row) * K + k0 + src8], &Bs[row * 32 + dst8]);
        }
        __syncthreads();
        bf16x8 af[4], bf[NF];
#pragma unroll
        for (int i = 0; i < 4; ++i)
            af[i] = *(const bf16x8*)&As[(wm + i * 16 + lr) * 32 + xq8];
#pragma unroll
        for (int i = 0; i < NF; ++i)
            bf[i] = *(const bf16x8*)&Bs[(wn + i * 16 + lr) * 32 + xq8];
#pragma unroll
        for (int mi = 0; mi < 4; ++mi)
#pragma unroll
            for (int ni = 0; ni < NF; ++ni)
                acc[mi][ni] = __builtin_amdgcn_mfma_f32_16x16x32_bf16(
                    af[mi], bf[ni], acc[mi][ni], 0, 0, 0);
        __syncthreads();
    }

#pragma unroll
    for (int mi = 0; mi < 4; ++mi) {
#pragma unroll
        for (int r = 0; r < 4; ++r) {
            int gr = m0 + wm + mi * 16 + quad * 4 + r;
#pragma unroll
            for (int ni = 0; ni < NF; ++ni) {
                int gc = n0 + wn + ni * 16 + lr;
                float v = acc[mi][ni][r] * sc;
                if constexpr (sizeof(OutT) == 2)
                    C[(size_t)gr * N + gc] = (OutT)f2bf(v);
                else
                    C[(size_t)gr * N + gc] = (OutT)v;
            }
        }
    }
}

// ---------------- V transpose: qkv[.,2048+h*64+d] -> vt[bh][d][s] ----------------
__global__ __launch_bounds__(256) void transpose_v(const u16* __restrict__ qkv,
                                                   u16* __restrict__ vt) {
    __shared__ alignas(16) u16 t[64][72];
    const int s0 = blockIdx.x * 64;
    const int bh = blockIdx.y;
    const int b = bh >> 4, h = bh & 15;
#pragma unroll
    for (int i = 0; i < 2; ++i) {
        int chunk = threadIdx.x + i * 256;
        int row = chunk >> 3;
        int c8 = (chunk & 7) * 8;
        uint4 v = *(const uint4*)&qkv[(size_t)(b * S_LEN + s0 + row) * QKV_W +
                                      2 * EMB + h * HD + c8];
        const u16* p = (const u16*)&v;
#pragma unroll
        for (int jj = 0; jj < 8; ++jj) t[c8 + jj][row] = p[jj];
    }
    __syncthreads();
#pragma unroll
    for (int i = 0; i < 2; ++i) {
        int chunk = threadIdx.x + i * 256;
        int d = chunk >> 3;
        int c8 = (chunk & 7) * 8;
        uint4 v = *(const uint4*)&t[d][c8];
        *(uint4*)&vt[((size_t)bh * HD + d) * S_LEN + s0 + c8] = v;
    }
}

// ---------------- Flash attention (causal), R14 structure + setprio ----------------
__global__ __launch_bounds__(256, 2) void attn(const u16* __restrict__ qkv,
                                               const u16* __restrict__ vt,
                                               u16* __restrict__ e) {
    const int tid = threadIdx.x;
    const int w = tid >> 6, lane = tid & 63;
    const int quad = lane >> 4, lr = lane & 15;
    const int g = w & 1, hv = w >> 1;
    const int y = blockIdx.y;
    const int tA = (y < 8) ? y : 23 - y;  // pair-balanced: co-resident pair sums to 49 iters
    const int tB = 31 - tA;
    const int bh = blockIdx.x, b = bh >> 4, h = bh & 15;

    __shared__ alignas(16) u16 smem[17408];  // 34816 B (K/V 32768; epi 34304)
    u16* Ks = smem;           // 2 buf x [d-half][kv row 64][32] = 8192 u16
    u16* Vs = smem + 8192;    // 2 buf x [kv-half][d row 64][32] = 8192 u16

    const u16* qkv_b = qkv + (size_t)b * S_LEN * QKV_W;
    bf16x8 qfA[2][2], qfB[2][2];
    int qgA[2], qgB[2];
#pragma unroll
    for (int f = 0; f < 2; ++f) {
        const u16* qra = qkv_b + (size_t)(tA * 64 + g * 32 + f * 16 + lr) * QKV_W + h * HD + quad * 8;
        const u16* qrb = qkv_b + (size_t)(tB * 64 + g * 32 + f * 16 + lr) * QKV_W + h * HD + quad * 8;
        qfA[f][0] = *(const bf16x8*)qra;
        qfA[f][1] = *(const bf16x8*)(qra + 32);
        qfB[f][0] = *(const bf16x8*)qrb;
        qfB[f][1] = *(const bf16x8*)(qrb + 32);
        qgA[f] = tA * 64 + g * 32 + f * 16 + lr;
        qgB[f] = tB * 64 + g * 32 + f * 16 + lr;
    }

    const u16* kbase = qkv_b + EMB + h * HD;          // K[s][d], stride 3072
    const u16* vbase = vt + (size_t)bh * HD * S_LEN;  // V^T[d][s], stride 2048

    f32x4 oA[2][4] = {}, oB[2][4] = {};
    float lsA[2] = {0.f, 0.f}, lsB[2] = {0.f, 0.f};

    const int sr = w * 16 + (lane >> 2);                     // dest row 0..63
    const int scl = (lane & 3) * 8;                          // dest chunk (linear)
    const int scg = ((lane & 3) ^ ((lane >> 3) & 3)) * 8;    // swizzled source chunk

    auto stage = [&](int j, int bb) {
        const int kv0 = j * 64;
        gld_lds16(kbase + (size_t)(kv0 + sr) * QKV_W + scg,
                  &Ks[bb * 4096 + sr * 32 + scl]);
        gld_lds16(kbase + (size_t)(kv0 + sr) * QKV_W + 32 + scg,
                  &Ks[bb * 4096 + 2048 + sr * 32 + scl]);
        gld_lds16(vbase + (size_t)sr * S_LEN + kv0 + scg,
                  &Vs[bb * 4096 + sr * 32 + scl]);
        gld_lds16(vbase + (size_t)sr * S_LEN + kv0 + 32 + scg,
                  &Vs[bb * 4096 + 2048 + sr * 32 + scl]);
    };

    const int xq8 = (quad ^ ((lr >> 1) & 3)) * 8;

    auto softpack = [&](const f32x4* s, bool diag, int qg, int kvg,
                        float& lsum) -> bf16x8 {
        float p[8];
#pragma unroll
        for (int nt = 0; nt < 2; ++nt)
#pragma unroll
            for (int r = 0; r < 4; ++r) {
                float pv = __builtin_amdgcn_exp2f(s[nt][r]);
                if (diag) pv = (kvg + nt * 16 + quad * 4 + r > qg) ? 0.f : pv;
                p[nt * 4 + r] = pv;
            }
        lsum += ((p[0] + p[1]) + (p[2] + p[3])) + ((p[4] + p[5]) + (p[6] + p[7]));
        unsigned x0 = __builtin_amdgcn_perm(__float_as_uint(p[1]),
                                            __float_as_uint(p[0]), 0x07060302u);
        unsigned x1 = __builtin_amdgcn_perm(__float_as_uint(p[3]),
                                            __float_as_uint(p[2]), 0x07060302u);
        unsigned x2 = __builtin_amdgcn_perm(__float_as_uint(p[5]),
                                            __float_as_uint(p[4]), 0x07060302u);
        unsigned x3 = __builtin_amdgcn_perm(__float_as_uint(p[7]),
                                            __float_as_uint(p[6]), 0x07060302u);
        asm("v_permlane32_swap_b32 %0, %1" : "+v"(x0), "+v"(x2));
        asm("v_permlane16_swap_b32 %0, %1" : "+v"(x0), "+v"(x2));
        asm("v_permlane32_swap_b32 %0, %1" : "+v"(x1), "+v"(x3));
        asm("v_permlane16_swap_b32 %0, %1" : "+v"(x1), "+v"(x3));
        union { unsigned u[4]; bf16x8 v; } r;
        r.u[0] = x0; r.u[1] = x1; r.u[2] = x2; r.u[3] = x3;
        return r.v;
    };

    stage(0, 0);
    for (int j = 0; j <= tB; ++j) {
        const int bb = j & 1;
        __syncthreads();  // staged buf bb complete; other buf free
        if (j < tB) stage(j + 1, 1 - bb);
        const bool doA = (j <= tA);
        const u16* ks = &Ks[bb * 4096];
        const u16* vs = &Vs[bb * 4096];
        const int kvh = hv * 32;  // this wave's kv-half within the tile

        bf16x8 k0[2], k1[2];
#pragma unroll
        for (int nt = 0; nt < 2; ++nt) {
            const int kvr = kvh + nt * 16 + lr;
            k0[nt] = *(const bf16x8*)&ks[kvr * 32 + xq8];
            k1[nt] = *(const bf16x8*)&ks[2048 + kvr * 32 + xq8];
        }
        f32x4 sB[2][2], sA[2][2];
        __builtin_amdgcn_s_setprio(1);
#pragma unroll
        for (int f = 0; f < 2; ++f)
#pragma unroll
            for (int nt = 0; nt < 2; ++nt) {
                f32x4 z = {};
                z = __builtin_amdgcn_mfma_f32_16x16x32_bf16(k0[nt], qfB[f][0], z, 0, 0, 0);
                z = __builtin_amdgcn_mfma_f32_16x16x32_bf16(k1[nt], qfB[f][1], z, 0, 0, 0);
                sB[f][nt] = z;
                if (doA) {
                    f32x4 za = {};
                    za = __builtin_amdgcn_mfma_f32_16x16x32_bf16(k0[nt], qfA[f][0], za, 0, 0, 0);
                    za = __builtin_amdgcn_mfma_f32_16x16x32_bf16(k1[nt], qfA[f][1], za, 0, 0, 0);
                    sA[f][nt] = za;
                }
            }
        __builtin_amdgcn_s_setprio(0);

        const int kvg = j * 64 + kvh;
        bf16x8 pB[2], pA[2];
#pragma unroll
        for (int f = 0; f < 2; ++f)
            pB[f] = softpack(sB[f], j == tB, qgB[f], kvg, lsB[f]);
        if (doA)
#pragma unroll
            for (int f = 0; f < 2; ++f)
                pA[f] = softpack(sA[f], j == tA, qgA[f], kvg, lsA[f]);

        __builtin_amdgcn_s_setprio(1);
#pragma unroll
        for (int nt = 0; nt < 4; ++nt) {
            bf16x8 v = *(const bf16x8*)&vs[hv * 2048 + (nt * 16 + lr) * 32 + xq8];
#pragma unroll
            for (int f = 0; f < 2; ++f) {
                oB[f][nt] = __builtin_amdgcn_mfma_f32_16x16x32_bf16(pB[f], v, oB[f][nt], 0, 0, 0);
                if (doA)
                    oA[f][nt] = __builtin_amdgcn_mfma_f32_16x16x32_bf16(pA[f], v, oA[f][nt], 0, 0, 0);
            }
        }
        __builtin_amdgcn_s_setprio(0);
    }

    float lfA[2], lfB[2];
#pragma unroll
    for (int f = 0; f < 2; ++f) {
        lfA[f] = lsA[f] + __shfl_xor(lsA[f], 16, 64);
        lfA[f] += __shfl_xor(lfA[f], 32, 64);
        lfB[f] = lsB[f] + __shfl_xor(lsB[f], 16, 64);
        lfB[f] += __shfl_xor(lfB[f], 32, 64);
    }
    __syncthreads();  // all compute done; K/V LDS dead -> reuse
    float* mA = (float*)smem;       // [64][66] f32 tile-A partials
    float* mB = mA + 64 * 66;       // [64][66] f32 tile-B partials
    float* lAr = mB + 64 * 66;      // [64] row sums (tile A, half 1)
    float* lBr = lAr + 64;          // [64] row sums (tile B, half 0)
    if (hv) {
#pragma unroll
        for (int f = 0; f < 2; ++f) {
#pragma unroll
            for (int nt = 0; nt < 4; ++nt)
#pragma unroll
                for (int r = 0; r < 4; ++r)
                    mA[(g * 32 + f * 16 + quad * 4 + r) * 66 + nt * 16 + lr] = oA[f][nt][r];
            if (lane < 16) lAr[g * 32 + f * 16 + lane] = lfA[f];
        }
    } else {
#pragma unroll
        for (int f = 0; f < 2; ++f) {
#pragma unroll
            for (int nt = 0; nt < 4; ++nt)
#pragma unroll
                for (int r = 0; r < 4; ++r)
                    mB[(g * 32 + f * 16 + quad * 4 + r) * 66 + nt * 16 + lr] = oB[f][nt][r];
            if (lane < 16) lBr[g * 32 + f * 16 + lane] = lfB[f];
        }
    }
    __syncthreads();
    if (!hv) {  // hv==0 waves finalize tile A
#pragma unroll
        for (int f = 0; f < 2; ++f) {
            float lff = lfA[f] + lAr[g * 32 + f * 16 + lr];
#pragma unroll
            for (int r = 0; r < 4; ++r) {
                float inv = 1.0f / __shfl(lff, quad * 4 + r, 64);
                size_t row = (size_t)(b * S_LEN + tA * 64 + g * 32 + f * 16 + quad * 4 + r) * EMB + h * HD;
#pragma unroll
                for (int nt = 0; nt < 4; ++nt)
                    e[row + nt * 16 + lr] =
                        f2bf((oA[f][nt][r] + mA[(g * 32 + f * 16 + quad * 4 + r) * 66 + nt * 16 + lr]) * inv);
            }
        }
    } else {  // hv==1 waves finalize tile B
#pragma unroll
        for (int f = 0; f < 2; ++f) {
            float lff = lfB[f] + lBr[g * 32 + f * 16 + lr];
#pragma unroll
            for (int r = 0; r < 4; ++r) {
                float inv = 1.0f / __shfl(lff, quad * 4 + r, 64);
                size_t row = (size_t)(b * S_LEN + tB * 64 + g * 32 + f * 16 + quad * 4 + r) * EMB + h * HD;
#pragma unroll
                for (int nt = 0; nt < 4; ++nt)
                    e[row + nt * 16 + lr] =
                        f2bf((oB[f][nt][r] + mB[(g * 32 + f * 16 + quad * 4 + r) * 66 + nt * 16 + lr]) * inv);
            }
        }
    }
}

// ---------------- launcher ----------------
extern "C" void kernel_launch(void* const* d_in, const int* in_sizes, int n_in,
                              void* d_out, int out_size, void* d_ws, size_t ws_size,
                              hipStream_t stream) {
    const float* x = (const float*)d_in[0];
    const float* w_qkv = (const float*)d_in[1];
    const float* w0 = (const float*)d_in[2];
    float* out = (float*)d_out;

    const size_t M = (size_t)BATCH * S_LEN;  // 4096
    u16* xb = (u16*)d_ws;
    u16* wqb = xb + M * EMB;
    u16* w0b = wqb + (size_t)QKV_W * EMB;
    u16* qkvb = w0b + (size_t)EMB * EMB;
    u16* vtb = qkvb + M * QKV_W;
    u16* eb = vtb + (size_t)BATCH * NH * HD * S_LEN;

    cvt_all<<<(XN4 + WQ4 + W04) / 256, 256, 0, stream>>>(x, w_qkv, w0, xb, wqb, w0b);

    // qkv = x @ w_qkv^T; grid x = m-tile (A-panel XCD-local), y = n-tile
    gemm_bt<u16, 128><<<dim3(M / 128, QKV_W / 128), 256, 0, stream>>>(
        xb, wqb, qkvb, (int)M, QKV_W, EMB, EMB);

    transpose_v<<<dim3(S_LEN / 64, BATCH * NH), 256, 0, stream>>>(qkvb, vtb);

    // grid x = bh so all pi-blocks of one head share an XCD (id%8 = bh%8)
    attn<<<dim3(BATCH * NH, 16), 256, 0, stream>>>(qkvb, vtb, eb);

    // out = e @ w0^T; grid x = m-tile (A-panel XCD-local), y = n-tile
    gemm_bt<float, 64><<<dim3(M / 128, EMB / 64), 256, 0, stream>>>(
        eb, w0b, out, (int)M, EMB, EMB, 0);
}

// Round 15
// 162.427 us; speedup vs baseline: 1.1562x; 1.0581x over previous
//
#include <hip/hip_runtime.h>

// MultiHeadSelfAttention: B=2, S=2048, E=1024, H=16, D=64
// bf16 MFMA pipeline. R23: abandon the single-tile attn arc (R19-R22: 3
// failure modes; R11-vs-R14 evidence shows waves/CU was never the lever).
// attn REVERTED to R18's proven paired-tile version (byte-identical).
// GEMMs: BK 32->64 (halves per-K barrier drains, the 2-phase structure's
// known ~20% residual) using the R16-hardware-verified 8-chunk-row swizzle:
// slot (row,ch) holds global chunk ch^(row&7); fragment read chunk
// (kh*4+quad)^(lr&7). Occupancy kept (qkv 32KB x 3/CU, out 24KB x 2/CU).
// cvt/transpose/launcher grids byte-identical to R18 (171.9us proven).

typedef unsigned short u16;
typedef short bf16x8 __attribute__((ext_vector_type(8)));
typedef float f32x4 __attribute__((ext_vector_type(4)));
typedef unsigned short u16x4 __attribute__((ext_vector_type(4)));

#define S_LEN 2048
#define EMB 1024
#define NH 16
#define HD 64
#define QKV_W 3072
#define BATCH 2
#define CSC 0.18033688f  // 0.125 * log2(e)

static __device__ __forceinline__ u16 f2bf(float f) {
    unsigned x = __float_as_uint(f);
    return (u16)((x + 0x7fffu + ((x >> 16) & 1u)) >> 16);
}

static __device__ __forceinline__ void gld_lds16(const u16* g, u16* l) {
    __builtin_amdgcn_global_load_lds(
        (const __attribute__((address_space(1))) void*)g,
        (__attribute__((address_space(3))) void*)l, 16, 0, 0);
}

// ---------------- fused fp32 -> bf16 casts (3 ranges) ----------------
#define XN4 (BATCH * S_LEN * EMB / 4)      // 1048576
#define WQ4 (QKV_W * EMB / 4)              // 786432
#define W04 (EMB * EMB / 4)                // 262144
__global__ __launch_bounds__(256) void cvt_all(const float* __restrict__ x,
                                               const float* __restrict__ wq,
                                               const float* __restrict__ w0,
                                               u16* __restrict__ xb,
                                               u16* __restrict__ wqb,
                                               u16* __restrict__ w0b) {
    int i = blockIdx.x * 256 + threadIdx.x;
    const float* src;
    u16* dst;
    int off;
    if (i < XN4) { src = x; dst = xb; off = i; }
    else if (i < XN4 + WQ4) { src = wq; dst = wqb; off = i - XN4; }
    else { src = w0; dst = w0b; off = i - XN4 - WQ4; }
    float4 v = ((const float4*)src)[off];
    u16x4 o;
    o[0] = f2bf(v.x); o[1] = f2bf(v.y); o[2] = f2bf(v.z); o[3] = f2bf(v.w);
    ((u16x4*)dst)[off] = o;
}

// ---------------- GEMM: C[M,N] = A[M,K] @ Bt[N,K]^T (128-tile, BK=64) ----
// BM=128, BN template (128 or 64), BK=64, 256 thr / 4 waves.
// GRID: blockIdx.x = m-tile (XCD = m%8 -> A-panel L2-local), blockIdx.y = n-tile.
// LDS rows are 64 u16 (8 chunks of 16B). XOR bank swizzle (R16-verified):
// slot (row, ch) holds global chunk ch ^ (row&7), staged via pre-swizzled
// global source (gld_lds dest linear); fragment reads for k-half kh at
// chunk (kh*4 + quad) ^ (lr&7)  (2-way residual = free).
template <typename OutT, int BN>
__global__ __launch_bounds__(256) void gemm_bt(const u16* __restrict__ A,
                                               const u16* __restrict__ Bt,
                                               OutT* __restrict__ C,
                                               int M, int N, int K, int qcols) {
    constexpr int NF = BN / 32;  // n-frags per wave
    __shared__ alignas(16) u16 As[128 * 64];
    __shared__ alignas(16) u16 Bs[BN * 64];
    const int tid = threadIdx.x;
    const int wave = tid >> 6, lane = tid & 63;
    const int quad = lane >> 4, lr = lane & 15;
    const int m0 = blockIdx.x * 128, n0 = blockIdx.y * BN;  // x = m-tile (XCD-local A)
    const int wm = (wave & 1) * 64, wn = (wave >> 1) * (BN / 2);
    const float sc = (n0 < qcols) ? CSC : 1.0f;

    f32x4 acc[4][NF] = {};
    const int xs8 = lr & 7;  // row-derived swizzle key for fragment reads

    for (int k0 = 0; k0 < K; k0 += 64) {
#pragma unroll
        for (int i = 0; i < 4; ++i) {          // A: 128 rows x 8 chunks
            int c = tid + i * 256;
            int row = c >> 3, ch = c & 7;
            gld_lds16(&A[(size_t)(m0 + row) * K + k0 + ((ch ^ (row & 7)) << 3)],
                      &As[row * 64 + ch * 8]);
        }
#pragma unroll
        for (int i = 0; i < BN / 32; ++i) {    // B: BN rows x 8 chunks
            int c = tid + i * 256;
            int row = c >> 3, ch = c & 7;
            gld_lds16(&Bt[(size_t)(n0 + row) * K + k0 + ((ch ^ (row & 7)) << 3)],
                      &Bs[row * 64 + ch * 8]);
        }
        __syncthreads();
#pragma unroll
        for (int kh = 0; kh < 2; ++kh) {
            const int cx = ((kh * 4 + quad) ^ xs8) << 3;
            bf16x8 af[4], bf[NF];
#pragma unroll
            for (int i = 0; i < 4; ++i)
                af[i] = *(const bf16x8*)&As[(wm + i * 16 + lr) * 64 + cx];
#pragma unroll
            for (int i = 0; i < NF; ++i)
                bf[i] = *(const bf16x8*)&Bs[(wn + i * 16 + lr) * 64 + cx];
#pragma unroll
            for (int mi = 0; mi < 4; ++mi)
#pragma unroll
                for (int ni = 0; ni < NF; ++ni)
                    acc[mi][ni] = __builtin_amdgcn_mfma_f32_16x16x32_bf16(
                        af[mi], bf[ni], acc[mi][ni], 0, 0, 0);
        }
        __syncthreads();
    }

#pragma unroll
    for (int mi = 0; mi < 4; ++mi) {
#pragma unroll
        for (int r = 0; r < 4; ++r) {
            int gr = m0 + wm + mi * 16 + quad * 4 + r;
#pragma unroll
            for (int ni = 0; ni < NF; ++ni) {
                int gc = n0 + wn + ni * 16 + lr;
                float v = acc[mi][ni][r] * sc;
                if constexpr (sizeof(OutT) == 2)
                    C[(size_t)gr * N + gc] = (OutT)f2bf(v);
                else
                    C[(size_t)gr * N + gc] = (OutT)v;
            }
        }
    }
}

// ---------------- V transpose: qkv[.,2048+h*64+d] -> vt[bh][d][s] ----------------
__global__ __launch_bounds__(256) void transpose_v(const u16* __restrict__ qkv,
                                                   u16* __restrict__ vt) {
    __shared__ alignas(16) u16 t[64][72];
    const int s0 = blockIdx.x * 64;
    const int bh = blockIdx.y;
    const int b = bh >> 4, h = bh & 15;
#pragma unroll
    for (int i = 0; i < 2; ++i) {
        int chunk = threadIdx.x + i * 256;
        int row = chunk >> 3;
        int c8 = (chunk & 7) * 8;
        uint4 v = *(const uint4*)&qkv[(size_t)(b * S_LEN + s0 + row) * QKV_W +
                                      2 * EMB + h * HD + c8];
        const u16* p = (const u16*)&v;
#pragma unroll
        for (int jj = 0; jj < 8; ++jj) t[c8 + jj][row] = p[jj];
    }
    __syncthreads();
#pragma unroll
    for (int i = 0; i < 2; ++i) {
        int chunk = threadIdx.x + i * 256;
        int d = chunk >> 3;
        int c8 = (chunk & 7) * 8;
        uint4 v = *(const uint4*)&t[d][c8];
        *(uint4*)&vt[((size_t)bh * HD + d) * S_LEN + s0 + c8] = v;
    }
}

// ---------------- Flash attention (causal), R18 structure (proven) ----------------
__global__ __launch_bounds__(256, 2) void attn(const u16* __restrict__ qkv,
                                               const u16* __restrict__ vt,
                                               u16* __restrict__ e) {
    const int tid = threadIdx.x;
    const int w = tid >> 6, lane = tid & 63;
    const int quad = lane >> 4, lr = lane & 15;
    const int g = w & 1, hv = w >> 1;
    const int y = blockIdx.y;
    const int tA = (y < 8) ? y : 23 - y;  // pair-balanced: co-resident pair sums to 49 iters
    const int tB = 31 - tA;
    const int bh = blockIdx.x, b = bh >> 4, h = bh & 15;

    __shared__ alignas(16) u16 smem[17408];  // 34816 B (K/V 32768; epi 34304)
    u16* Ks = smem;           // 2 buf x [d-half][kv row 64][32] = 8192 u16
    u16* Vs = smem + 8192;    // 2 buf x [kv-half][d row 64][32] = 8192 u16

    const u16* qkv_b = qkv + (size_t)b * S_LEN * QKV_W;
    bf16x8 qfA[2][2], qfB[2][2];
    int qgA[2], qgB[2];
#pragma unroll
    for (int f = 0; f < 2; ++f) {
        const u16* qra = qkv_b + (size_t)(tA * 64 + g * 32 + f * 16 + lr) * QKV_W + h * HD + quad * 8;
        const u16* qrb = qkv_b + (size_t)(tB * 64 + g * 32 + f * 16 + lr) * QKV_W + h * HD + quad * 8;
        qfA[f][0] = *(const bf16x8*)qra;
        qfA[f][1] = *(const bf16x8*)(qra + 32);
        qfB[f][0] = *(const bf16x8*)qrb;
        qfB[f][1] = *(const bf16x8*)(qrb + 32);
        qgA[f] = tA * 64 + g * 32 + f * 16 + lr;
        qgB[f] = tB * 64 + g * 32 + f * 16 + lr;
    }

    const u16* kbase = qkv_b + EMB + h * HD;          // K[s][d], stride 3072
    const u16* vbase = vt + (size_t)bh * HD * S_LEN;  // V^T[d][s], stride 2048

    f32x4 oA[2][4] = {}, oB[2][4] = {};
    float lsA[2] = {0.f, 0.f}, lsB[2] = {0.f, 0.f};

    const int sr = w * 16 + (lane >> 2);                     // dest row 0..63
    const int scl = (lane & 3) * 8;                          // dest chunk (linear)
    const int scg = ((lane & 3) ^ ((lane >> 3) & 3)) * 8;    // swizzled source chunk

    auto stage = [&](int j, int bb) {
        const int kv0 = j * 64;
        gld_lds16(kbase + (size_t)(kv0 + sr) * QKV_W + scg,
                  &Ks[bb * 4096 + sr * 32 + scl]);
        gld_lds16(kbase + (size_t)(kv0 + sr) * QKV_W + 32 + scg,
                  &Ks[bb * 4096 + 2048 + sr * 32 + scl]);
        gld_lds16(vbase + (size_t)sr * S_LEN + kv0 + scg,
                  &Vs[bb * 4096 + sr * 32 + scl]);
        gld_lds16(vbase + (size_t)sr * S_LEN + kv0 + 32 + scg,
                  &Vs[bb * 4096 + 2048 + sr * 32 + scl]);
    };

    const int xq8 = (quad ^ ((lr >> 1) & 3)) * 8;

    auto softpack = [&](const f32x4* s, bool diag, int qg, int kvg,
                        float& lsum) -> bf16x8 {
        float p[8];
#pragma unroll
        for (int nt = 0; nt < 2; ++nt)
#pragma unroll
            for (int r = 0; r < 4; ++r) {
                float pv = __builtin_amdgcn_exp2f(s[nt][r]);
                if (diag) pv = (kvg + nt * 16 + quad * 4 + r > qg) ? 0.f : pv;
                p[nt * 4 + r] = pv;
            }
        lsum += ((p[0] + p[1]) + (p[2] + p[3])) + ((p[4] + p[5]) + (p[6] + p[7]));
        unsigned x0 = __builtin_amdgcn_perm(__float_as_uint(p[1]),
                                            __float_as_uint(p[0]), 0x07060302u);
        unsigned x1 = __builtin_amdgcn_perm(__float_as_uint(p[3]),
                                            __float_as_uint(p[2]), 0x07060302u);
        unsigned x2 = __builtin_amdgcn_perm(__float_as_uint(p[5]),
                                            __float_as_uint(p[4]), 0x07060302u);
        unsigned x3 = __builtin_amdgcn_perm(__float_as_uint(p[7]),
                                            __float_as_uint(p[6]), 0x07060302u);
        asm("v_permlane32_swap_b32 %0, %1" : "+v"(x0), "+v"(x2));
        asm("v_permlane16_swap_b32 %0, %1" : "+v"(x0), "+v"(x2));
        asm("v_permlane32_swap_b32 %0, %1" : "+v"(x1), "+v"(x3));
        asm("v_permlane16_swap_b32 %0, %1" : "+v"(x1), "+v"(x3));
        union { unsigned u[4]; bf16x8 v; } r;
        r.u[0] = x0; r.u[1] = x1; r.u[2] = x2; r.u[3] = x3;
        return r.v;
    };

    stage(0, 0);
    for (int j = 0; j <= tB; ++j) {
        const int bb = j & 1;
        __syncthreads();  // staged buf bb complete; other buf free
        if (j < tB) stage(j + 1, 1 - bb);
        const bool doA = (j <= tA);
        const u16* ks = &Ks[bb * 4096];
        const u16* vs = &Vs[bb * 4096];
        const int kvh = hv * 32;  // this wave's kv-half within the tile

        bf16x8 k0[2], k1[2];
#pragma unroll
        for (int nt = 0; nt < 2; ++nt) {
            const int kvr = kvh + nt * 16 + lr;
            k0[nt] = *(const bf16x8*)&ks[kvr * 32 + xq8];
            k1[nt] = *(const bf16x8*)&ks[2048 + kvr * 32 + xq8];
        }
        f32x4 sB[2][2], sA[2][2];
        __builtin_amdgcn_s_setprio(1);
#pragma unroll
        for (int f = 0; f < 2; ++f)
#pragma unroll
            for (int nt = 0; nt < 2; ++nt) {
                f32x4 z = {};
                z = __builtin_amdgcn_mfma_f32_16x16x32_bf16(k0[nt], qfB[f][0], z, 0, 0, 0);
                z = __builtin_amdgcn_mfma_f32_16x16x32_bf16(k1[nt], qfB[f][1], z, 0, 0, 0);
                sB[f][nt] = z;
                if (doA) {
                    f32x4 za = {};
                    za = __builtin_amdgcn_mfma_f32_16x16x32_bf16(k0[nt], qfA[f][0], za, 0, 0, 0);
                    za = __builtin_amdgcn_mfma_f32_16x16x32_bf16(k1[nt], qfA[f][1], za, 0, 0, 0);
                    sA[f][nt] = za;
                }
            }
        __builtin_amdgcn_s_setprio(0);

        const int kvg = j * 64 + kvh;
        bf16x8 pB[2], pA[2];
#pragma unroll
        for (int f = 0; f < 2; ++f)
            pB[f] = softpack(sB[f], j == tB, qgB[f], kvg, lsB[f]);
        if (doA)
#pragma unroll
            for (int f = 0; f < 2; ++f)
                pA[f] = softpack(sA[f], j == tA, qgA[f], kvg, lsA[f]);

        __builtin_amdgcn_s_setprio(1);
#pragma unroll
        for (int nt = 0; nt < 4; ++nt) {
            bf16x8 v = *(const bf16x8*)&vs[hv * 2048 + (nt * 16 + lr) * 32 + xq8];
#pragma unroll
            for (int f = 0; f < 2; ++f) {
                oB[f][nt] = __builtin_amdgcn_mfma_f32_16x16x32_bf16(pB[f], v, oB[f][nt], 0, 0, 0);
                if (doA)
                    oA[f][nt] = __builtin_amdgcn_mfma_f32_16x16x32_bf16(pA[f], v, oA[f][nt], 0, 0, 0);
            }
        }
        __builtin_amdgcn_s_setprio(0);
    }

    float lfA[2], lfB[2];
#pragma unroll
    for (int f = 0; f < 2; ++f) {
        lfA[f] = lsA[f] + __shfl_xor(lsA[f], 16, 64);
        lfA[f] += __shfl_xor(lfA[f], 32, 64);
        lfB[f] = lsB[f] + __shfl_xor(lsB[f], 16, 64);
        lfB[f] += __shfl_xor(lfB[f], 32, 64);
    }
    __syncthreads();  // all compute done; K/V LDS dead -> reuse
    float* mA = (float*)smem;       // [64][66] f32 tile-A partials
    float* mB = mA + 64 * 66;       // [64][66] f32 tile-B partials
    float* lAr = mB + 64 * 66;      // [64] row sums (tile A, half 1)
    float* lBr = lAr + 64;          // [64] row sums (tile B, half 0)
    if (hv) {
#pragma unroll
        for (int f = 0; f < 2; ++f) {
#pragma unroll
            for (int nt = 0; nt < 4; ++nt)
#pragma unroll
                for (int r = 0; r < 4; ++r)
                    mA[(g * 32 + f * 16 + quad * 4 + r) * 66 + nt * 16 + lr] = oA[f][nt][r];
            if (lane < 16) lAr[g * 32 + f * 16 + lane] = lfA[f];
        }
    } else {
#pragma unroll
        for (int f = 0; f < 2; ++f) {
#pragma unroll
            for (int nt = 0; nt < 4; ++nt)
#pragma unroll
                for (int r = 0; r < 4; ++r)
                    mB[(g * 32 + f * 16 + quad * 4 + r) * 66 + nt * 16 + lr] = oB[f][nt][r];
            if (lane < 16) lBr[g * 32 + f * 16 + lane] = lfB[f];
        }
    }
    __syncthreads();
    if (!hv) {  // hv==0 waves finalize tile A
#pragma unroll
        for (int f = 0; f < 2; ++f) {
            float lff = lfA[f] + lAr[g * 32 + f * 16 + lr];
#pragma unroll
            for (int r = 0; r < 4; ++r) {
                float inv = 1.0f / __shfl(lff, quad * 4 + r, 64);
                size_t row = (size_t)(b * S_LEN + tA * 64 + g * 32 + f * 16 + quad * 4 + r) * EMB + h * HD;
#pragma unroll
                for (int nt = 0; nt < 4; ++nt)
                    e[row + nt * 16 + lr] =
                        f2bf((oA[f][nt][r] + mA[(g * 32 + f * 16 + quad * 4 + r) * 66 + nt * 16 + lr]) * inv);
            }
        }
    } else {  // hv==1 waves finalize tile B
#pragma unroll
        for (int f = 0; f < 2; ++f) {
            float lff = lfB[f] + lBr[g * 32 + f * 16 + lr];
#pragma unroll
            for (int r = 0; r < 4; ++r) {
                float inv = 1.0f / __shfl(lff, quad * 4 + r, 64);
                size_t row = (size_t)(b * S_LEN + tB * 64 + g * 32 + f * 16 + quad * 4 + r) * EMB + h * HD;
#pragma unroll
                for (int nt = 0; nt < 4; ++nt)
                    e[row + nt * 16 + lr] =
                        f2bf((oB[f][nt][r] + mB[(g * 32 + f * 16 + quad * 4 + r) * 66 + nt * 16 + lr]) * inv);
            }
        }
    }
}

// ---------------- launcher ----------------
extern "C" void kernel_launch(void* const* d_in, const int* in_sizes, int n_in,
                              void* d_out, int out_size, void* d_ws, size_t ws_size,
                              hipStream_t stream) {
    const float* x = (const float*)d_in[0];
    const float* w_qkv = (const float*)d_in[1];
    const float* w0 = (const float*)d_in[2];
    float* out = (float*)d_out;

    const size_t M = (size_t)BATCH * S_LEN;  // 4096
    u16* xb = (u16*)d_ws;
    u16* wqb = xb + M * EMB;
    u16* w0b = wqb + (size_t)QKV_W * EMB;
    u16* qkvb = w0b + (size_t)EMB * EMB;
    u16* vtb = qkvb + M * QKV_W;
    u16* eb = vtb + (size_t)BATCH * NH * HD * S_LEN;

    cvt_all<<<(XN4 + WQ4 + W04) / 256, 256, 0, stream>>>(x, w_qkv, w0, xb, wqb, w0b);

    // qkv = x @ w_qkv^T; grid x = m-tile (A-panel XCD-local), y = n-tile
    gemm_bt<u16, 128><<<dim3(M / 128, QKV_W / 128), 256, 0, stream>>>(
        xb, wqb, qkvb, (int)M, QKV_W, EMB, EMB);

    transpose_v<<<dim3(S_LEN / 64, BATCH * NH), 256, 0, stream>>>(qkvb, vtb);

    // grid x = bh so all pi-blocks of one head share an XCD (id%8 = bh%8)
    attn<<<dim3(BATCH * NH, 16), 256, 0, stream>>>(qkvb, vtb, eb);

    // out = e @ w0^T; grid x = m-tile (A-panel XCD-local), y = n-tile
    gemm_bt<float, 64><<<dim3(M / 128, EMB / 64), 256, 0, stream>>>(
        eb, w0b, out, (int)M, EMB, EMB, 0);
}